// Round 12
// baseline (340.778 us; speedup 1.0000x reference)
//
#include <hip/hip_runtime.h>
#include <math.h>

// Problem constants (from reference)
constexpr int D = 64;
constexpr int NU = 50000, NB = 20000, NI = 100000;
constexpr int BATCH = 2048, NCAND = 2, MAXDEG = 50, CORE_K = 3;
constexpr int PAD_IDX = NI;
constexpr int N_UB = NU + NB, N_UI = NU + NI, N_BI = NB + NI;
constexpr int N_TOT = N_UB + N_UI + N_BI;   // 340000 combined node space
constexpr int OFF1 = N_UB;                  // UI node base
constexpr int OFF2 = N_UB + N_UI;           // BI node base
constexpr int CAP = 48;                     // fixed bucket capacity per row
constexpr float VAL_SCALE = 16383.0f / 0.2f;    // val in [0,0.2) -> 14-bit fixed
constexpr float VAL_INV   = 0.2f / 16383.0f;

// ---- global feature table (R17): dedup'd gather target ----
constexpr int GB_BASE = NU;            // 50000
constexpr int GI_BASE = NU + NB;       // 70000
constexpr int NGF = NU + NB + NI;      // 170000 (< 2^18, fits cv col field)

// ---- two-level binning (R14/R20/R23/R25) ----
// R25: phase-C stores SORTED by (bucket,lo) via LDS counting sort. R24 showed
// the kernel is bound by store-transaction rate (VALU 7%, HBM 19%, occ 60%,
// yet slower with MORE waves): lane-adjacent stores hit different buckets ->
// no coalescing -> 3M separate L2 transactions. Sorted order makes adjacent
// lanes write consecutive slots -> runs coalesce into 1-2 transactions.
constexpr int BSHIFT = 9;
constexpr int BROWS  = 1 << BSHIFT;                      // 512 rows/bucket
constexpr int NBUCK  = (N_TOT + BROWS - 1) >> BSHIFT;    // 665
constexpr int BCAP   = 6144;     // bucket mean ~4510, sigma ~67 -> 24 sigma margin
constexpr int P1_EPT = 8;        // edges per thread in pass 1
constexpr int P1_TPB = 256;
constexpr int P1_EPB = P1_EPT * P1_TPB;                  // 2048 edges/block
constexpr int P1_CHUNK = (NBUCK + P1_TPB - 1) / P1_TPB;  // 3 buckets/thread

// ---- demand-driven layer 2 (R16) + compact slot-indexed output (R17) ----
constexpr int L2_NCB = BATCH * NCAND;                    // 4096 candidate bundles
constexpr int L2_SLOTS = 2 * NI + 2 * BATCH + 2 * L2_NCB;  // 212288
constexpr int S_UBU = 2 * NI;                // UB user slots
constexpr int S_UIU = 2 * NI + BATCH;        // UI user slots
constexpr int S_UBB = 2 * NI + 2 * BATCH;    // UB bundle slots
constexpr int S_BIB = S_UBB + L2_NCB;        // BI bundle slots

// ---- demand-driven layer 1 (R21/R24): flags ----
constexpr int MARK_A_BLOCKS = (L2_NCB * MAXDEG + 255) / 256;   // 800
constexpr int MARK_D_BLOCKS = (BATCH + L2_NCB + 255) / 256;    // 24

__device__ __forceinline__ float wave_sum64(float v) {
#pragma unroll
    for (int off = 32; off > 0; off >>= 1) v += __shfl_down(v, off);
    return v;  // valid in lane 0
}

// ---- bf16 via raw bit ops (no API surface; RNE pack, <<16 unpack) ----
__device__ __forceinline__ float bflo(unsigned u) { return __uint_as_float(u << 16); }
__device__ __forceinline__ float bfhi(unsigned u) { return __uint_as_float(u & 0xFFFF0000u); }
__device__ __forceinline__ unsigned short f2bf(float f) {
    unsigned u = __float_as_uint(f);
    u += 0x7FFF + ((u >> 16) & 1);      // round-nearest-even
    return (unsigned short)(u >> 16);
}
__device__ __forceinline__ unsigned pack2(float a, float b) {
    return (unsigned)f2bf(a) | ((unsigned)f2bf(b) << 16);
}
__device__ __forceinline__ float bf1(const unsigned short* p) {
    return __uint_as_float(((unsigned)*p) << 16);
}

__device__ __forceinline__ void edge_decode(unsigned u, int& col, float& v) {
    col = (int)(u & 0x3FFFFu);
    v = (float)(u >> 18) * VAL_INV;
}

// ---------------- K1: coarse binning + cvt + demand seeds (R24/R25) ---------
// block ranges: [0,nb1) bin1 | [nb1,nb2) cvt | [nb2,nb3) fS | [nb3,...) du/db
__global__ __launch_bounds__(256) void k_bin1cvt(
    const int* __restrict__ r0, const int* __restrict__ c0,
    const float* __restrict__ v0,
    const int* __restrict__ r1, const int* __restrict__ c1,
    const float* __restrict__ v1,
    const int* __restrict__ r2, const int* __restrict__ c2,
    const float* __restrict__ v2,
    int e0, int e1, int e2, int nb1, int nb2, int nb3,
    int* __restrict__ bcnt, uint2* __restrict__ stage,
    const float* __restrict__ uf, const float* __restrict__ bf,
    const float* __restrict__ itf, unsigned short* __restrict__ gt,
    const int* __restrict__ users, const int* __restrict__ bundles,
    const int* __restrict__ bundle_items,
    unsigned char* __restrict__ fS, unsigned char* __restrict__ du,
    unsigned char* __restrict__ db) {
    const int t = threadIdx.x;
    const int bid = (int)blockIdx.x;
    if (bid >= nb3) {
        // ---- du/db: demanded user/bundle row seeds ----
        int q = (bid - nb3) * 256 + t;
        if (q < BATCH) du[users[q]] = 1;
        else if (q < BATCH + L2_NCB) db[bundles[q - BATCH]] = 1;
        return;
    }
    if (bid >= nb2) {
        // ---- fS: items in candidate bundles ----
        int i = (bid - nb2) * 256 + t;
        if (i < L2_NCB * MAXDEG) {
            int it = bundle_items[(size_t)bundles[i / MAXDEG] * MAXDEG + (i % MAXDEG)];
            if (it != PAD_IDX) fS[it] = 1;
        }
        return;
    }
    if (bid >= nb1) {
        // ---- cvt part ----
        size_t i = (size_t)(bid - nb1) * 256 + t;   // 4-element group
        if (i >= (size_t)NGF * 16) return;
        int row = (int)(i >> 4);
        int q = ((int)i & 15) * 4;
        const float* src;
        if (row < GB_BASE)      src = uf  + (size_t)row * D;
        else if (row < GI_BASE) src = bf  + (size_t)(row - GB_BASE) * D;
        else                    src = itf + (size_t)(row - GI_BASE) * D;
        float4 v = *(const float4*)(src + q);
        ushort4 o;
        o.x = f2bf(v.x); o.y = f2bf(v.y); o.z = f2bf(v.z); o.w = f2bf(v.w);
        *(ushort4*)(gt + (size_t)row * D + q) = o;
        return;
    }
    // ---- bin1 part (R25: LDS counting sort -> coalesced stage stores) ----
    __shared__ int s_hist[NBUCK];        // 2.7 KB
    __shared__ int s_start[NBUCK];       // 2.7 KB (block-local bucket starts)
    __shared__ unsigned s_base[NBUCK];   // 2.7 KB (global bucket bases)
    __shared__ int s_psum[P1_TPB];       // 1 KB scan scratch
    __shared__ uint2 s_ed[P1_EPB];       // 16 KB unsorted edges
    __shared__ uint2 s_ed2[P1_EPB];      // 16 KB sorted edges
    const int etot = e0 + e1 + e2;
    const int i0 = bid * P1_EPB + t;
    for (int l = t; l < NBUCK; l += P1_TPB) s_hist[l] = 0;
    __syncthreads();
    // phase A: single edge read; hist atomic; stash {payload, r|lo<<19}
#pragma unroll
    for (int k = 0; k < P1_EPT; ++k) {
        int i = i0 + k * P1_TPB;
        uint2 ed = make_uint2(0u, 0xFFFFFFFFu);
        if (i < etot) {
            int r, g; float v;
            if (i < e0)           { r = r0[i]; g = c0[i]; v = v0[i]; }
            else if (i < e0 + e1) { int j = i - e0; r = r1[j] + OFF1;
                                    int c = c1[j]; g = (c < NU) ? c : c + NB; v = v1[j]; }
            else                  { int j = i - e0 - e1; r = r2[j] + OFF2;
                                    g = c2[j] + NU; v = v2[j]; }
            unsigned q = (unsigned)fminf(v * VAL_SCALE + 0.5f, 16383.0f);
            int lo = atomicAdd(&s_hist[r >> BSHIFT], 1);   // LDS atomic
            ed = make_uint2((q << 18) | (unsigned)g,
                            (unsigned)r | ((unsigned)lo << 19));  // r:19b, lo:13b
        }
        s_ed[k * P1_TPB + t] = ed;
    }
    __syncthreads();
    // block prefix-sum of s_hist -> s_start (3 buckets/thread + block scan)
    const int cbase = t * P1_CHUNK;
    int mysum = 0;
#pragma unroll
    for (int c = 0; c < P1_CHUNK; ++c) {
        int idx = cbase + c;
        if (idx < NBUCK) mysum += s_hist[idx];
    }
    s_psum[t] = mysum;
    __syncthreads();
    for (int ofs = 1; ofs < P1_TPB; ofs <<= 1) {
        int v = (t >= ofs) ? s_psum[t - ofs] : 0;
        __syncthreads();
        s_psum[t] += v;
        __syncthreads();
    }
    int run = s_psum[t] - mysum;   // exclusive prefix of this chunk
#pragma unroll
    for (int c = 0; c < P1_CHUNK; ++c) {
        int idx = cbase + c;
        if (idx < NBUCK) { s_start[idx] = run; run += s_hist[idx]; }
    }
    // phase B: reserve global runs
    for (int l = t; l < NBUCK; l += P1_TPB)
        s_base[l] = (unsigned)atomicAdd(&bcnt[l], s_hist[l]);
    __syncthreads();
    // LDS scatter: sorted by (bucket, lo)
#pragma unroll
    for (int k = 0; k < P1_EPT; ++k) {
        uint2 e = s_ed[k * P1_TPB + t];
        if (e.y == 0xFFFFFFFFu) continue;
        unsigned r = e.y & 0x7FFFFu;
        int b = (int)(r >> BSHIFT);
        s_ed2[s_start[b] + (int)(e.y >> 19)] = e;
    }
    __syncthreads();
    // phase C: sequential walk of sorted edges -> coalesced global stores
    int nblk = etot - bid * P1_EPB; if (nblk > P1_EPB) nblk = P1_EPB;
    for (int j = t; j < nblk; j += P1_TPB) {
        uint2 e = s_ed2[j];
        unsigned r = e.y & 0x7FFFFu;
        unsigned b = r >> BSHIFT;
        unsigned slot = s_base[b] + (e.y >> 19);
        if (slot < (unsigned)BCAP)
            stage[(size_t)b * BCAP + slot] = make_uint2(e.x, r);
    }
}

// ---------------- K2: bucket refine + f1/f2 marking (R20/R24) ---------------
__global__ __launch_bounds__(1024) void k_bin2(
    const int* __restrict__ bcnt, const uint2* __restrict__ stage,
    const unsigned char* __restrict__ du, const unsigned char* __restrict__ db,
    int* __restrict__ cnt, unsigned* __restrict__ cv,
    unsigned char* __restrict__ f1, unsigned char* __restrict__ f2) {
    __shared__ unsigned lcv[BROWS][CAP];   // 96 KB
    __shared__ int s_c[BROWS];             // 2 KB
    const int b = blockIdx.x;
    const int t = threadIdx.x;
    if (t < BROWS) s_c[t] = 0;
    __syncthreads();
    int nb = bcnt[b]; if (nb > BCAP) nb = BCAP;
    const uint2* sp = stage + (size_t)b * BCAP;
    const int rbase = b << BSHIFT;
    for (int i = t; i < nb; i += 1024) {
        uint2 e = sp[i];
        int rl = (int)e.y - rbase;
        int slot = atomicAdd(&s_c[rl], 1);   // LDS atomic
        if (slot < CAP) lcv[rl][slot] = e.x;
    }
    __syncthreads();
    if (t < BROWS && rbase + t < N_TOT) cnt[rbase + t] = s_c[t];
    // f1/f2 marking for demanded UI-user / BI-bundle rows (LDS scan)
    if (t < BROWS) {
        int r = rbase + t;
        unsigned char* f = nullptr;
        if (r >= OFF1 && r < OFF1 + NU)      { if (du[r - OFF1]) f = f1; }
        else if (r >= OFF2 && r < OFF2 + NB) { if (db[r - OFF2]) f = f2; }
        if (f) {
            int deg = s_c[t]; if (deg > CAP) deg = CAP;
            for (int j = 0; j < deg; ++j) {
                int g = (int)(lcv[t][j] & 0x3FFFFu);
                if (g >= GI_BASE) f[g - GI_BASE] = 1;
            }
        }
    }
    // phase B: 64 groups of 16 lanes; group g writes rows g, g+64, ...
    const int g16 = t >> 4;
    const int l16 = t & 15;
#pragma unroll 1
    for (int rl = g16; rl < BROWS; rl += 64) {
        int r = rbase + rl;
        if (r >= N_TOT) continue;
        int deg = s_c[rl]; if (deg > CAP) deg = CAP;
        if (deg == 0) continue;
        int nwords = (deg + 15) & ~15;      // round up to 64B line
        if (l16 * 4 < nwords) {
            uint4 w = *(const uint4*)&lcv[rl][l16 * 4];
            *(uint4*)(cv + (size_t)r * CAP + l16 * 4) = w;
        }
    }
}

// ---------------- K3: layer 1, DEMAND-DRIVEN (R21) --------------------------
__global__ __launch_bounds__(256) void k_spmm_l1(
    const int* __restrict__ cnt, const unsigned* __restrict__ cv,
    const unsigned short* __restrict__ gt,
    const unsigned char* __restrict__ f1, const unsigned char* __restrict__ f2,
    unsigned short* __restrict__ y1) {
    int r = blockIdx.x * 32 + (threadIdx.x >> 3);
    int t = threadIdx.x & 7;            // 8 bf16 features per lane
    if (r >= N_TOT) return;
    // item-row demand check (user/bundle rows always needed)
    if (r >= OFF1 + NU && r < OFF2) { if (!f1[r - OFF1 - NU]) return; }
    else if (r >= OFF2 + NB)        { if (!f2[r - OFF2 - NB]) return; }
    int deg = cnt[r]; if (deg > CAP) deg = CAP;
    const unsigned* ce = cv + (size_t)r * CAP;
    float a[8];
#pragma unroll
    for (int k = 0; k < 8; ++k) a[k] = 0.f;
    int j = 0;
    for (; j + 3 < deg; j += 4) {
        int c[4]; float v[4]; uint4 u[4];
#pragma unroll
        for (int k = 0; k < 4; ++k) edge_decode(ce[j + k], c[k], v[k]);
#pragma unroll
        for (int k = 0; k < 4; ++k)
            u[k] = *(const uint4*)(gt + (((size_t)c[k]) << 6) + t * 8);
#pragma unroll
        for (int k = 0; k < 4; ++k) {
            a[0] = fmaf(v[k], bflo(u[k].x), a[0]); a[1] = fmaf(v[k], bfhi(u[k].x), a[1]);
            a[2] = fmaf(v[k], bflo(u[k].y), a[2]); a[3] = fmaf(v[k], bfhi(u[k].y), a[3]);
            a[4] = fmaf(v[k], bflo(u[k].z), a[4]); a[5] = fmaf(v[k], bfhi(u[k].z), a[5]);
            a[6] = fmaf(v[k], bflo(u[k].w), a[6]); a[7] = fmaf(v[k], bfhi(u[k].w), a[7]);
        }
    }
    for (; j < deg; ++j) {
        int c0; float v0;
        edge_decode(ce[j], c0, v0);
        uint4 u0 = *(const uint4*)(gt + (((size_t)c0) << 6) + t * 8);
        a[0] = fmaf(v0, bflo(u0.x), a[0]); a[1] = fmaf(v0, bfhi(u0.x), a[1]);
        a[2] = fmaf(v0, bflo(u0.y), a[2]); a[3] = fmaf(v0, bfhi(u0.y), a[3]);
        a[4] = fmaf(v0, bflo(u0.z), a[4]); a[5] = fmaf(v0, bfhi(u0.z), a[5]);
        a[6] = fmaf(v0, bflo(u0.w), a[6]); a[7] = fmaf(v0, bfhi(u0.w), a[7]);
    }
    uint4 o;
    o.x = pack2(a[0], a[1]); o.y = pack2(a[2], a[3]);
    o.z = pack2(a[4], a[5]); o.w = pack2(a[6], a[7]);
    *(uint4*)(y1 + ((size_t)r << 6) + t * 8) = o;
}

// ---------------- K4: layer 2 + mean, demand-driven, compact output --------
__global__ __launch_bounds__(256) void k_spmm_l2(
    const int* __restrict__ cnt, const unsigned* __restrict__ cv,
    const int* __restrict__ users, const int* __restrict__ bundles,
    const unsigned short* __restrict__ y1, const unsigned short* __restrict__ gt,
    const unsigned char* __restrict__ fS,
    unsigned short* __restrict__ xc) {
    int s = blockIdx.x * 32 + (threadIdx.x >> 3);
    int t = threadIdx.x & 7;
    if (s >= L2_SLOTS) return;
    int r, g, sec;
    if (s < NI)                { if (!fS[s]) return;                   // R21
                                 r = OFF1 + NU + s;        g = GI_BASE + s;        sec = 1; }
    else if (s < 2 * NI)       { int i = s - NI; if (!fS[i]) return;   // R21
                                 r = OFF2 + NB + i;        g = GI_BASE + i;        sec = 2; }
    else {
        int q = s - 2 * NI;
        if (q < BATCH)            { int u = users[q];             r = u;         g = u;            sec = 0; }
        else if (q < 2 * BATCH)   { int u = users[q - BATCH];     r = OFF1 + u;  g = u;            sec = 1; }
        else if (q < S_BIB - 2 * NI) { int b = bundles[q - 2 * BATCH];
                                    r = NU + b;    g = GB_BASE + b;  sec = 0; }
        else                      { int b = bundles[q - (S_BIB - 2 * NI)];
                                    r = OFF2 + b;  g = GB_BASE + b;  sec = 2; }
    }
    // inverse map: global feature idx -> y1 row in this section
    auto y1row = [&](int gg) -> int {
        if (sec == 0) return gg;                       // UB
        if (sec == 2) return OFF2 - GB_BASE + gg;      // BI
        return OFF1 + ((gg < NU) ? gg : gg - NB);      // UI
    };
    int deg = cnt[r]; if (deg > CAP) deg = CAP;
    const unsigned* ce = cv + (size_t)r * CAP;
    float a[8];
#pragma unroll
    for (int k = 0; k < 8; ++k) a[k] = 0.f;
    int j = 0;
    for (; j + 3 < deg; j += 4) {
        int c[4]; float v[4]; uint4 u[4];
#pragma unroll
        for (int k = 0; k < 4; ++k) edge_decode(ce[j + k], c[k], v[k]);
#pragma unroll
        for (int k = 0; k < 4; ++k)
            u[k] = *(const uint4*)(y1 + (((size_t)y1row(c[k])) << 6) + t * 8);
#pragma unroll
        for (int k = 0; k < 4; ++k) {
            a[0] = fmaf(v[k], bflo(u[k].x), a[0]); a[1] = fmaf(v[k], bfhi(u[k].x), a[1]);
            a[2] = fmaf(v[k], bflo(u[k].y), a[2]); a[3] = fmaf(v[k], bfhi(u[k].y), a[3]);
            a[4] = fmaf(v[k], bflo(u[k].z), a[4]); a[5] = fmaf(v[k], bfhi(u[k].z), a[5]);
            a[6] = fmaf(v[k], bflo(u[k].w), a[6]); a[7] = fmaf(v[k], bfhi(u[k].w), a[7]);
        }
    }
    for (; j < deg; ++j) {
        int c0; float v0;
        edge_decode(ce[j], c0, v0);
        uint4 u0 = *(const uint4*)(y1 + (((size_t)y1row(c0)) << 6) + t * 8);
        a[0] = fmaf(v0, bflo(u0.x), a[0]); a[1] = fmaf(v0, bfhi(u0.x), a[1]);
        a[2] = fmaf(v0, bflo(u0.y), a[2]); a[3] = fmaf(v0, bfhi(u0.y), a[3]);
        a[4] = fmaf(v0, bflo(u0.z), a[4]); a[5] = fmaf(v0, bfhi(u0.z), a[5]);
        a[6] = fmaf(v0, bflo(u0.w), a[6]); a[7] = fmaf(v0, bfhi(u0.w), a[7]);
    }
    uint4 fx = *(const uint4*)(gt + ((size_t)g << 6) + t * 8);   // original feature
    uint4 yx = *(const uint4*)(y1 + ((size_t)r << 6) + t * 8);
    constexpr float k3 = 1.0f / 3.0f;
    float o[8];
    o[0] = (bflo(fx.x) + bflo(yx.x) + a[0]) * k3;
    o[1] = (bfhi(fx.x) + bfhi(yx.x) + a[1]) * k3;
    o[2] = (bflo(fx.y) + bflo(yx.y) + a[2]) * k3;
    o[3] = (bfhi(fx.y) + bfhi(yx.y) + a[3]) * k3;
    o[4] = (bflo(fx.z) + bflo(yx.z) + a[4]) * k3;
    o[5] = (bfhi(fx.z) + bfhi(yx.z) + a[5]) * k3;
    o[6] = (bflo(fx.w) + bflo(yx.w) + a[6]) * k3;
    o[7] = (bfhi(fx.w) + bfhi(yx.w) + a[7]) * k3;
    uint4 w;
    w.x = pack2(o[0], o[1]); w.y = pack2(o[2], o[3]);
    w.z = pack2(o[4], o[5]); w.w = pack2(o[6], o[7]);
    *(uint4*)(xc + ((size_t)s << 6) + t * 8) = w;
}

// ---------------- K5: scoring + fused BPR loss (R18, kept) ----------------
__global__ __launch_bounds__(256) void k_score(
    const int* __restrict__ bundles,
    const int* __restrict__ bundle_items,
    const unsigned short* __restrict__ xc,
    const float* __restrict__ cw1, const float* __restrict__ cb1,
    const float* __restrict__ cw2, const float* __restrict__ cb2,
    const float* __restrict__ sw1, const float* __restrict__ sb1,
    const float* __restrict__ sw2, const float* __restrict__ sb2,
    float* __restrict__ accum, unsigned* __restrict__ tick,
    float* __restrict__ out) {
    const int t  = threadIdx.x;
    const int wv = t >> 6;               // wave 0..3 -> candidate
    const int ln = t & 63;
    const int n  = blockIdx.x * 4 + wv;  // grid = BATCH*NCAND/4
    const int g8 = ln >> 3;              // item subgroup (8 items in flight)
    const int l8 = ln & 7;               // feature octet within item
    const int uq = n >> 1;               // batch index
    const int b = bundles[n];

    __shared__ unsigned sh_it[4][MAXDEG][32];  // items_ui bf16: 50 x 64 (25.6 KB)
    __shared__ float sh_r[4][2][MAXDEG];       // dual dot results
    __shared__ float sh_syn[4][2 * D];         // [hcore | hfringe]
    __shared__ float sh_h1[4][D];              // relu(syn @ sw1 + sb1)
    __shared__ float sh_sc[4];                 // per-wave final scores

    int my_idx = (ln < MAXDEG) ? bundle_items[(size_t)b * MAXDEG + ln] : PAD_IDX;
    unsigned long long vmask = __ballot(my_idx != PAD_IDX);

    uint4 ufr = *(const uint4*)(xc + (((size_t)(S_UIU + uq)) << 6) + l8 * 8);
    uint4 bfr = *(const uint4*)(xc + (((size_t)(S_BIB + n)) << 6) + l8 * 8);
    float uf0 = bflo(ufr.x), uf1 = bfhi(ufr.x), uf2 = bflo(ufr.y), uf3 = bfhi(ufr.y);
    float uf4 = bflo(ufr.z), uf5 = bfhi(ufr.z), uf6 = bflo(ufr.w), uf7 = bfhi(ufr.w);
    float bf0 = bflo(bfr.x), bf1_ = bfhi(bfr.x), bf2 = bflo(bfr.y), bf3 = bfhi(bfr.y);
    float bf4 = bflo(bfr.z), bf5 = bfhi(bfr.z), bf6 = bflo(bfr.w), bf7 = bfhi(bfr.w);

    // --- P1: 50 dual dots, 8 items in flight x 8 lanes x 8 features ---
    for (int iter = 0; iter < (MAXDEG + 7) / 8; ++iter) {
        int m = iter * 8 + g8;
        if (m >= MAXDEG) continue;
        int it = __shfl(my_idx, m);
        uint4 iu = make_uint4(0, 0, 0, 0);
        float pu = 0.f, pb = 0.f;
        if (it != PAD_IDX) {
            iu = *(const uint4*)(xc + (((size_t)it) << 6) + l8 * 8);              // UI item
            uint4 ib = *(const uint4*)(xc + (((size_t)(NI + it)) << 6) + l8 * 8); // BI item
            pu = uf0 * bflo(iu.x) + uf1 * bfhi(iu.x) + uf2 * bflo(iu.y) + uf3 * bfhi(iu.y)
               + uf4 * bflo(iu.z) + uf5 * bfhi(iu.z) + uf6 * bflo(iu.w) + uf7 * bfhi(iu.w);
            pb = bf0 * bflo(ib.x) + bf1_ * bfhi(ib.x) + bf2 * bflo(ib.y) + bf3 * bfhi(ib.y)
               + bf4 * bflo(ib.z) + bf5 * bfhi(ib.z) + bf6 * bflo(ib.w) + bf7 * bfhi(ib.w);
        }
        *(uint4*)&sh_it[wv][m][l8 * 4] = iu;   // pads stash zeros
#pragma unroll
        for (int off = 4; off > 0; off >>= 1) {
            pu += __shfl_down(pu, off, 8);
            pb += __shfl_down(pb, off, 8);
        }
        if (l8 == 0) { sh_r[wv][0][m] = pu; sh_r[wv][1][m] = pb; }
    }
    __builtin_amdgcn_wave_barrier();

    // --- P2: core MLP (2->32->1), lane m = item m ---
    float logit = -INFINITY;
    if (ln < MAXDEG && my_idx != PAD_IDX) {
        float rU = sh_r[wv][0][ln], rB = sh_r[wv][1][ln];
        float acc = cb2[0];
#pragma unroll
        for (int j = 0; j < 32; ++j) {
            float h = fmaf(rU, cw1[j], fmaf(rB, cw1[32 + j], cb1[j]));
            h = fmaxf(h, 0.f);
            acc = fmaf(h, cw2[j], acc);
        }
        logit = acc;
    }

    // --- P3: wave-parallel softmax + top-3 ---
    float mx = logit;
#pragma unroll
    for (int off = 32; off > 0; off >>= 1) mx = fmaxf(mx, __shfl_xor(mx, off));
    float e = expf(logit - mx);            // pad lanes: exp(-inf)=0
    float sm = e;
#pragma unroll
    for (int off = 32; off > 0; off >>= 1) sm += __shfl_xor(sm, off);
    float p = e / sm;

    int ti[CORE_K]; float tp[CORE_K];
    float vsel = p;
#pragma unroll
    for (int k = 0; k < CORE_K; ++k) {
        float vv = vsel; int ii = ln;
#pragma unroll
        for (int off = 32; off > 0; off >>= 1) {
            float v2 = __shfl_xor(vv, off);
            int   i2 = __shfl_xor(ii, off);
            if (v2 > vv || (v2 == vv && i2 < ii)) { vv = v2; ii = i2; }
        }
        ti[k] = ii; tp[k] = vv;            // uniform across wave
        if (ln == ii) vsel = -1.f;
    }
    float tinv = 1.f / (tp[0] + tp[1] + tp[2] + 1e-10f);
    tp[0] *= tinv; tp[1] *= tinv; tp[2] *= tinv;

    // --- P4: h_core / h_fringe, lane = feature dim ---
    int ti0 = ti[0], ti1 = ti[1], ti2 = ti[2];
    const int ui_w = ln >> 1;
    const bool hi = (ln & 1);
    auto feat = [&](int m) -> float {
        unsigned w = sh_it[wv][m][ui_w];
        return hi ? bfhi(w) : bflo(w);
    };
    float hcore = feat(ti0) * tp[0] + feat(ti1) * tp[1] + feat(ti2) * tp[2];
    float fsum = 0.f;
#pragma unroll 10
    for (int m = 0; m < MAXDEG; ++m) fsum += feat(m);   // pads contribute 0
    int fcnt = __popcll(vmask);
#pragma unroll
    for (int k = 0; k < CORE_K; ++k) {
        if ((vmask >> ti[k]) & 1ull) { fsum -= feat(ti[k]); fcnt--; }
    }
    float hfr = fsum / fmaxf((float)fcnt, 1.f);
    sh_syn[wv][ln] = hcore;
    sh_syn[wv][D + ln] = hfr;
    __builtin_amdgcn_wave_barrier();

    // --- P5: synergy MLP (128->64 relu ->64), whole wave, LDS broadcast ---
    float h1 = sb1[ln];
#pragma unroll 8
    for (int k0 = 0; k0 < 32; ++k0) {
        float4 s4 = *(const float4*)&sh_syn[wv][k0 * 4];
        h1 = fmaf(s4.x, sw1[(k0 * 4 + 0) * D + ln], h1);
        h1 = fmaf(s4.y, sw1[(k0 * 4 + 1) * D + ln], h1);
        h1 = fmaf(s4.z, sw1[(k0 * 4 + 2) * D + ln], h1);
        h1 = fmaf(s4.w, sw1[(k0 * 4 + 3) * D + ln], h1);
    }
    sh_h1[wv][ln] = fmaxf(h1, 0.f);
    __builtin_amdgcn_wave_barrier();
    float phi = sb2[ln];
#pragma unroll 8
    for (int k0 = 0; k0 < 16; ++k0) {
        float4 s4 = *(const float4*)&sh_h1[wv][k0 * 4];
        phi = fmaf(s4.x, sw2[(k0 * 4 + 0) * D + ln], phi);
        phi = fmaf(s4.y, sw2[(k0 * 4 + 1) * D + ln], phi);
        phi = fmaf(s4.z, sw2[(k0 * 4 + 2) * D + ln], phi);
        phi = fmaf(s4.w, sw2[(k0 * 4 + 3) * D + ln], phi);
    }

    // --- P6: final score ---
    float hat = hcore + phi;
    float uui = bf1(xc + (((size_t)(S_UIU + uq)) << 6) + ln);
    float ubu = bf1(xc + (((size_t)(S_UBU + uq)) << 6) + ln);
    float ubb = bf1(xc + (((size_t)(S_UBB + n)) << 6) + ln);
    float part = wave_sum64(uui * ubb + ubu * hat);
    if (ln == 0) sh_sc[wv] = part;

    // --- fused BPR loss tail: pairs (wv 0,1) and (wv 2,3) ---
    __syncthreads();
    if (t == 0) {
        float x01 = sh_sc[1] - sh_sc[0];
        float x23 = sh_sc[3] - sh_sc[2];
        float spv = fmaxf(x01, 0.f) + log1pf(expf(-fabsf(x01)))
                  + fmaxf(x23, 0.f) + log1pf(expf(-fabsf(x23)));
        atomicAdd(accum, spv * (1.0f / (float)BATCH));
        __threadfence();
        unsigned old = atomicAdd(tick, 1u);
        if (old == gridDim.x - 1) {          // last block: publish
            __threadfence();
            float total = atomicAdd(accum, 0.0f);   // coherent RMW read
            out[0] = total;
        }
    }
}

extern "C" void kernel_launch(void* const* d_in, const int* in_sizes, int n_in,
                              void* d_out, int out_size, void* d_ws, size_t ws_size,
                              hipStream_t stream) {
    const float* users_feature   = (const float*)d_in[0];
    const float* bundles_feature = (const float*)d_in[1];
    const float* items_feature   = (const float*)d_in[2];
    const float* cw1 = (const float*)d_in[3];
    const float* cb1 = (const float*)d_in[4];
    const float* cw2 = (const float*)d_in[5];
    const float* cb2 = (const float*)d_in[6];
    const float* sw1 = (const float*)d_in[7];
    const float* sb1 = (const float*)d_in[8];
    const float* sw2 = (const float*)d_in[9];
    const float* sb2 = (const float*)d_in[10];
    const float* ub_val = (const float*)d_in[11];
    const float* ui_val = (const float*)d_in[12];
    const float* bi_val = (const float*)d_in[13];
    const int* users   = (const int*)d_in[14];
    const int* bundles = (const int*)d_in[15];
    const int* ub_row = (const int*)d_in[16];
    const int* ub_col = (const int*)d_in[17];
    const int* ui_row = (const int*)d_in[18];
    const int* ui_col = (const int*)d_in[19];
    const int* bi_row = (const int*)d_in[20];
    const int* bi_col = (const int*)d_in[21];
    const int* bundle_items = (const int*)d_in[22];
    const int E_UB = in_sizes[11], E_UI = in_sizes[12], E_BI = in_sizes[13];
    const int E_TOT = E_UB + E_UI + E_BI;

    // workspace layout (4-byte units), ~163 MB (< ~167 MB proven in R1)
    float* ws = (float*)d_ws;
    size_t off = 0;
    unsigned short* gt  = (unsigned short*)(ws + off); off += (size_t)NGF * 32;      // 21.8 MB
    unsigned short* y1b = (unsigned short*)(ws + off); off += (size_t)N_TOT * 32;    // 43.5 MB
    unsigned* cv  = (unsigned*)(ws + off); off += (size_t)N_TOT * CAP;               // 65.3 MB
    // stage (32.7 MB) overlays xc (27.2 MB): stage dead after k_bin2,
    // xc written only by k_spmm_l2 (later kernel).
    uint2* stage = (uint2*)(ws + off);
    unsigned short* xc = (unsigned short*)(ws + off);
    off += (size_t)NBUCK * BCAP * 2;                                                 // 32.7 MB
    // memset region: [bcnt | tick | accum | fS | f1 | f2 | du | db]
    int*   bcnt   = (int*)(ws + off); off += NBUCK;
    unsigned* tick = (unsigned*)(ws + off); off += 1;
    float* accum  = (float*)(ws + off); off += 1;
    unsigned char* fS = (unsigned char*)(ws + off); off += NI / 4;
    unsigned char* f1 = (unsigned char*)(ws + off); off += NI / 4;
    unsigned char* f2 = (unsigned char*)(ws + off); off += NI / 4;
    unsigned char* du = (unsigned char*)(ws + off); off += NU / 4;
    unsigned char* db = (unsigned char*)(ws + off); off += NB / 4;
    int*   cnt    = (int*)(ws + off); off += N_TOT;
    if (ws_size < off * sizeof(float)) return;  // fail loudly (wrong answer)

    // zero bcnt + tick + accum + flags (fS,f1,f2,du,db) in one memset
    hipMemsetAsync(bcnt, 0, (NBUCK + 2) * sizeof(int) + 3 * NI + NU + NB, stream);

    // K1: coarse binning + feature convert + demand seeds (merged; R25)
    const int nb1 = (E_TOT + P1_EPB - 1) / P1_EPB;
    const int ncvt = (int)(((size_t)NGF * 16 + 255) / 256);
    const int nb2 = nb1 + ncvt;
    const int nb3 = nb2 + MARK_A_BLOCKS;
    k_bin1cvt<<<nb3 + MARK_D_BLOCKS, P1_TPB, 0, stream>>>(
        ub_row, ub_col, ub_val, ui_row, ui_col, ui_val, bi_row, bi_col, bi_val,
        E_UB, E_UI, E_BI, nb1, nb2, nb3, bcnt, stage,
        users_feature, bundles_feature, items_feature, gt,
        users, bundles, bundle_items, fS, du, db);

    // K2: per-bucket refine + f1/f2 marking (R24: k_mark folded in)
    k_bin2<<<NBUCK, 1024, 0, stream>>>(bcnt, stage, du, db, cnt, cv, f1, f2);

    // K3: demand-driven layer-1 gather
    k_spmm_l1<<<(N_TOT + 31) / 32, 256, 0, stream>>>(cnt, cv, gt, f1, f2, y1b);

    // K4: demand-driven layer 2 -> compact xc
    k_spmm_l2<<<(L2_SLOTS + 31) / 32, 256, 0, stream>>>(
        cnt, cv, users, bundles, y1b, gt, fS, xc);

    // K5: scoring + fused loss
    k_score<<<(BATCH * NCAND) / 4, 256, 0, stream>>>(
        bundles, bundle_items, xc,
        cw1, cb1, cw2, cb2, sw1, sb1, sw2, sb2,
        accum, tick, (float*)d_out);
}

// Round 13
// 329.319 us; speedup vs baseline: 1.0348x; 1.0348x over previous
//
#include <hip/hip_runtime.h>
#include <math.h>

// Problem constants (from reference)
constexpr int D = 64;
constexpr int NU = 50000, NB = 20000, NI = 100000;
constexpr int BATCH = 2048, NCAND = 2, MAXDEG = 50, CORE_K = 3;
constexpr int PAD_IDX = NI;
constexpr int N_UB = NU + NB, N_UI = NU + NI, N_BI = NB + NI;
constexpr int N_TOT = N_UB + N_UI + N_BI;   // 340000 combined node space
constexpr int OFF1 = N_UB;                  // UI node base
constexpr int OFF2 = N_UB + N_UI;           // BI node base
constexpr int CAP = 48;                     // fixed bucket capacity per row
constexpr float VAL_SCALE = 16383.0f / 0.2f;    // val in [0,0.2) -> 14-bit fixed
constexpr float VAL_INV   = 0.2f / 16383.0f;

// ---- global feature table (R17): dedup'd gather target ----
constexpr int GB_BASE = NU;            // 50000
constexpr int GI_BASE = NU + NB;       // 70000
constexpr int NGF = NU + NB + NI;      // 170000 (< 2^18, fits cv col field)

// ---- two-level binning (R14/R20/R23/R26) ----
// R26: revert bin1 to the proven R23 form (EPT=16, LDS-staged edges, 56us —
// the floor across 5 structural variants: spill 57 / re-read 92 / LDS 56 /
// small-EPT 65 / sorted 70). Keep ONLY R24's k_mark fold (isolated now).
constexpr int BSHIFT = 9;
constexpr int BROWS  = 1 << BSHIFT;                      // 512 rows/bucket
constexpr int NBUCK  = (N_TOT + BROWS - 1) >> BSHIFT;    // 665
constexpr int BCAP   = 6144;     // bucket mean ~4510, sigma ~67 -> 24 sigma margin
constexpr int P1_EPT = 16;       // edges per thread in pass 1 (R23 value)
constexpr int P1_TPB = 256;
constexpr int P1_EPB = P1_EPT * P1_TPB;                  // 4096 edges/block

// ---- demand-driven layer 2 (R16) + compact slot-indexed output (R17) ----
constexpr int L2_NCB = BATCH * NCAND;                    // 4096 candidate bundles
constexpr int L2_SLOTS = 2 * NI + 2 * BATCH + 2 * L2_NCB;  // 212288
constexpr int S_UBU = 2 * NI;                // UB user slots
constexpr int S_UIU = 2 * NI + BATCH;        // UI user slots
constexpr int S_UBB = 2 * NI + 2 * BATCH;    // UB bundle slots
constexpr int S_BIB = S_UBB + L2_NCB;        // BI bundle slots

// ---- demand-driven layer 1 (R21/R24): flags ----
// fS[i]: item in some candidate bundle  (set in bin1cvt spare blocks)
// du[u]/db[b]: user/bundle is demanded  (set in bin1cvt spare blocks)
// f1[i]/f2[i]: item adjacent to demanded user/bundle (set in bin2 from LDS)
constexpr int MARK_A_BLOCKS = (L2_NCB * MAXDEG + 255) / 256;   // 800
constexpr int MARK_D_BLOCKS = (BATCH + L2_NCB + 255) / 256;    // 24

__device__ __forceinline__ float wave_sum64(float v) {
#pragma unroll
    for (int off = 32; off > 0; off >>= 1) v += __shfl_down(v, off);
    return v;  // valid in lane 0
}

// ---- bf16 via raw bit ops (no API surface; RNE pack, <<16 unpack) ----
__device__ __forceinline__ float bflo(unsigned u) { return __uint_as_float(u << 16); }
__device__ __forceinline__ float bfhi(unsigned u) { return __uint_as_float(u & 0xFFFF0000u); }
__device__ __forceinline__ unsigned short f2bf(float f) {
    unsigned u = __float_as_uint(f);
    u += 0x7FFF + ((u >> 16) & 1);      // round-nearest-even
    return (unsigned short)(u >> 16);
}
__device__ __forceinline__ unsigned pack2(float a, float b) {
    return (unsigned)f2bf(a) | ((unsigned)f2bf(b) << 16);
}
__device__ __forceinline__ float bf1(const unsigned short* p) {
    return __uint_as_float(((unsigned)*p) << 16);
}

__device__ __forceinline__ void edge_decode(unsigned u, int& col, float& v) {
    col = (int)(u & 0x3FFFFu);
    v = (float)(u >> 18) * VAL_INV;
}

// ---------------- K1: coarse binning + cvt + demand seeds (R23/R26) ---------
// block ranges: [0,nb1) bin1 | [nb1,nb2) cvt | [nb2,nb3) fS | [nb3,...) du/db
__global__ __launch_bounds__(256) void k_bin1cvt(
    const int* __restrict__ r0, const int* __restrict__ c0,
    const float* __restrict__ v0,
    const int* __restrict__ r1, const int* __restrict__ c1,
    const float* __restrict__ v1,
    const int* __restrict__ r2, const int* __restrict__ c2,
    const float* __restrict__ v2,
    int e0, int e1, int e2, int nb1, int nb2, int nb3,
    int* __restrict__ bcnt, uint2* __restrict__ stage,
    const float* __restrict__ uf, const float* __restrict__ bf,
    const float* __restrict__ itf, unsigned short* __restrict__ gt,
    const int* __restrict__ users, const int* __restrict__ bundles,
    const int* __restrict__ bundle_items,
    unsigned char* __restrict__ fS, unsigned char* __restrict__ du,
    unsigned char* __restrict__ db) {
    const int t = threadIdx.x;
    const int bid = (int)blockIdx.x;
    if (bid >= nb3) {
        // ---- du/db: demanded user/bundle row seeds ----
        int q = (bid - nb3) * 256 + t;
        if (q < BATCH) du[users[q]] = 1;
        else if (q < BATCH + L2_NCB) db[bundles[q - BATCH]] = 1;
        return;
    }
    if (bid >= nb2) {
        // ---- fS: items in candidate bundles ----
        int i = (bid - nb2) * 256 + t;
        if (i < L2_NCB * MAXDEG) {
            int it = bundle_items[(size_t)bundles[i / MAXDEG] * MAXDEG + (i % MAXDEG)];
            if (it != PAD_IDX) fS[it] = 1;
        }
        return;
    }
    if (bid >= nb1) {
        // ---- cvt part ----
        size_t i = (size_t)(bid - nb1) * 256 + t;   // 4-element group
        if (i >= (size_t)NGF * 16) return;
        int row = (int)(i >> 4);
        int q = ((int)i & 15) * 4;
        const float* src;
        if (row < GB_BASE)      src = uf  + (size_t)row * D;
        else if (row < GI_BASE) src = bf  + (size_t)(row - GB_BASE) * D;
        else                    src = itf + (size_t)(row - GI_BASE) * D;
        float4 v = *(const float4*)(src + q);
        ushort4 o;
        o.x = f2bf(v.x); o.y = f2bf(v.y); o.z = f2bf(v.z); o.w = f2bf(v.w);
        *(ushort4*)(gt + (size_t)row * D + q) = o;
        return;
    }
    // ---- bin1 part (R23: LDS-staged per-edge state, single edge read) ----
    __shared__ int s_hist[NBUCK];        // 2.7 KB
    __shared__ unsigned s_base[NBUCK];   // 2.7 KB
    __shared__ uint2 s_ed[P1_EPB];       // 32 KB edge staging (kills scratch)
    const int etot = e0 + e1 + e2;
    const int i0 = bid * P1_EPB + t;
    for (int l = t; l < NBUCK; l += P1_TPB) s_hist[l] = 0;
    __syncthreads();
    // phase A: single edge read; hist atomic; stash {payload, r|lo<<19} in LDS
#pragma unroll
    for (int k = 0; k < P1_EPT; ++k) {
        int i = i0 + k * P1_TPB;
        uint2 ed = make_uint2(0u, 0xFFFFFFFFu);
        if (i < etot) {
            int r, g; float v;
            if (i < e0)           { r = r0[i]; g = c0[i]; v = v0[i]; }
            else if (i < e0 + e1) { int j = i - e0; r = r1[j] + OFF1;
                                    int c = c1[j]; g = (c < NU) ? c : c + NB; v = v1[j]; }
            else                  { int j = i - e0 - e1; r = r2[j] + OFF2;
                                    g = c2[j] + NU; v = v2[j]; }
            unsigned q = (unsigned)fminf(v * VAL_SCALE + 0.5f, 16383.0f);
            int lo = atomicAdd(&s_hist[r >> BSHIFT], 1);   // LDS atomic
            ed = make_uint2((q << 18) | (unsigned)g,
                            (unsigned)r | ((unsigned)lo << 19));  // r:19b, lo:13b
        }
        s_ed[k * P1_TPB + t] = ed;       // coalesced LDS store
    }
    __syncthreads();
    // phase B: reserve global runs
    for (int l = t; l < NBUCK; l += P1_TPB)
        s_base[l] = (unsigned)atomicAdd(&bcnt[l], s_hist[l]);
    __syncthreads();
    // phase C: replay from LDS; tight scatter loop
#pragma unroll
    for (int k = 0; k < P1_EPT; ++k) {
        uint2 e = s_ed[k * P1_TPB + t];
        if (e.y == 0xFFFFFFFFu) continue;
        unsigned r = e.y & 0x7FFFFu;
        unsigned b = r >> BSHIFT;
        unsigned slot = s_base[b] + (e.y >> 19);
        if (slot < (unsigned)BCAP)
            stage[(size_t)b * BCAP + slot] = make_uint2(e.x, r);
    }
}

// ---------------- K2: bucket refine + f1/f2 marking (R20/R24) ---------------
// Demanded-row neighbor marking folded here — the row's edge list is already
// in LDS (lcv), so the scan is LDS reads, and the k_mark dispatch disappears.
__global__ __launch_bounds__(1024) void k_bin2(
    const int* __restrict__ bcnt, const uint2* __restrict__ stage,
    const unsigned char* __restrict__ du, const unsigned char* __restrict__ db,
    int* __restrict__ cnt, unsigned* __restrict__ cv,
    unsigned char* __restrict__ f1, unsigned char* __restrict__ f2) {
    __shared__ unsigned lcv[BROWS][CAP];   // 96 KB
    __shared__ int s_c[BROWS];             // 2 KB
    const int b = blockIdx.x;
    const int t = threadIdx.x;
    if (t < BROWS) s_c[t] = 0;
    __syncthreads();
    int nb = bcnt[b]; if (nb > BCAP) nb = BCAP;
    const uint2* sp = stage + (size_t)b * BCAP;
    const int rbase = b << BSHIFT;
    for (int i = t; i < nb; i += 1024) {
        uint2 e = sp[i];
        int rl = (int)e.y - rbase;
        int slot = atomicAdd(&s_c[rl], 1);   // LDS atomic
        if (slot < CAP) lcv[rl][slot] = e.x;
    }
    __syncthreads();
    if (t < BROWS && rbase + t < N_TOT) cnt[rbase + t] = s_c[t];
    // f1/f2 marking for demanded UI-user / BI-bundle rows (LDS scan)
    if (t < BROWS) {
        int r = rbase + t;
        unsigned char* f = nullptr;
        if (r >= OFF1 && r < OFF1 + NU)      { if (du[r - OFF1]) f = f1; }
        else if (r >= OFF2 && r < OFF2 + NB) { if (db[r - OFF2]) f = f2; }
        if (f) {
            int deg = s_c[t]; if (deg > CAP) deg = CAP;
            for (int j = 0; j < deg; ++j) {
                int g = (int)(lcv[t][j] & 0x3FFFFu);
                if (g >= GI_BASE) f[g - GI_BASE] = 1;
            }
        }
    }
    // phase B: 64 groups of 16 lanes; group g writes rows g, g+64, ...
    const int g16 = t >> 4;
    const int l16 = t & 15;
#pragma unroll 1
    for (int rl = g16; rl < BROWS; rl += 64) {
        int r = rbase + rl;
        if (r >= N_TOT) continue;
        int deg = s_c[rl]; if (deg > CAP) deg = CAP;
        if (deg == 0) continue;
        int nwords = (deg + 15) & ~15;      // round up to 64B line
        if (l16 * 4 < nwords) {
            uint4 w = *(const uint4*)&lcv[rl][l16 * 4];
            *(uint4*)(cv + (size_t)r * CAP + l16 * 4) = w;
        }
    }
}

// ---------------- K3: layer 1, DEMAND-DRIVEN (R21) --------------------------
__global__ __launch_bounds__(256) void k_spmm_l1(
    const int* __restrict__ cnt, const unsigned* __restrict__ cv,
    const unsigned short* __restrict__ gt,
    const unsigned char* __restrict__ f1, const unsigned char* __restrict__ f2,
    unsigned short* __restrict__ y1) {
    int r = blockIdx.x * 32 + (threadIdx.x >> 3);
    int t = threadIdx.x & 7;            // 8 bf16 features per lane
    if (r >= N_TOT) return;
    // item-row demand check (user/bundle rows always needed)
    if (r >= OFF1 + NU && r < OFF2) { if (!f1[r - OFF1 - NU]) return; }
    else if (r >= OFF2 + NB)        { if (!f2[r - OFF2 - NB]) return; }
    int deg = cnt[r]; if (deg > CAP) deg = CAP;
    const unsigned* ce = cv + (size_t)r * CAP;
    float a[8];
#pragma unroll
    for (int k = 0; k < 8; ++k) a[k] = 0.f;
    int j = 0;
    for (; j + 3 < deg; j += 4) {
        int c[4]; float v[4]; uint4 u[4];
#pragma unroll
        for (int k = 0; k < 4; ++k) edge_decode(ce[j + k], c[k], v[k]);
#pragma unroll
        for (int k = 0; k < 4; ++k)
            u[k] = *(const uint4*)(gt + (((size_t)c[k]) << 6) + t * 8);
#pragma unroll
        for (int k = 0; k < 4; ++k) {
            a[0] = fmaf(v[k], bflo(u[k].x), a[0]); a[1] = fmaf(v[k], bfhi(u[k].x), a[1]);
            a[2] = fmaf(v[k], bflo(u[k].y), a[2]); a[3] = fmaf(v[k], bfhi(u[k].y), a[3]);
            a[4] = fmaf(v[k], bflo(u[k].z), a[4]); a[5] = fmaf(v[k], bfhi(u[k].z), a[5]);
            a[6] = fmaf(v[k], bflo(u[k].w), a[6]); a[7] = fmaf(v[k], bfhi(u[k].w), a[7]);
        }
    }
    for (; j < deg; ++j) {
        int c0; float v0;
        edge_decode(ce[j], c0, v0);
        uint4 u0 = *(const uint4*)(gt + (((size_t)c0) << 6) + t * 8);
        a[0] = fmaf(v0, bflo(u0.x), a[0]); a[1] = fmaf(v0, bfhi(u0.x), a[1]);
        a[2] = fmaf(v0, bflo(u0.y), a[2]); a[3] = fmaf(v0, bfhi(u0.y), a[3]);
        a[4] = fmaf(v0, bflo(u0.z), a[4]); a[5] = fmaf(v0, bfhi(u0.z), a[5]);
        a[6] = fmaf(v0, bflo(u0.w), a[6]); a[7] = fmaf(v0, bfhi(u0.w), a[7]);
    }
    uint4 o;
    o.x = pack2(a[0], a[1]); o.y = pack2(a[2], a[3]);
    o.z = pack2(a[4], a[5]); o.w = pack2(a[6], a[7]);
    *(uint4*)(y1 + ((size_t)r << 6) + t * 8) = o;
}

// ---------------- K4: layer 2 + mean, demand-driven, compact output --------
__global__ __launch_bounds__(256) void k_spmm_l2(
    const int* __restrict__ cnt, const unsigned* __restrict__ cv,
    const int* __restrict__ users, const int* __restrict__ bundles,
    const unsigned short* __restrict__ y1, const unsigned short* __restrict__ gt,
    const unsigned char* __restrict__ fS,
    unsigned short* __restrict__ xc) {
    int s = blockIdx.x * 32 + (threadIdx.x >> 3);
    int t = threadIdx.x & 7;
    if (s >= L2_SLOTS) return;
    int r, g, sec;
    if (s < NI)                { if (!fS[s]) return;                   // R21
                                 r = OFF1 + NU + s;        g = GI_BASE + s;        sec = 1; }
    else if (s < 2 * NI)       { int i = s - NI; if (!fS[i]) return;   // R21
                                 r = OFF2 + NB + i;        g = GI_BASE + i;        sec = 2; }
    else {
        int q = s - 2 * NI;
        if (q < BATCH)            { int u = users[q];             r = u;         g = u;            sec = 0; }
        else if (q < 2 * BATCH)   { int u = users[q - BATCH];     r = OFF1 + u;  g = u;            sec = 1; }
        else if (q < S_BIB - 2 * NI) { int b = bundles[q - 2 * BATCH];
                                    r = NU + b;    g = GB_BASE + b;  sec = 0; }
        else                      { int b = bundles[q - (S_BIB - 2 * NI)];
                                    r = OFF2 + b;  g = GB_BASE + b;  sec = 2; }
    }
    // inverse map: global feature idx -> y1 row in this section
    auto y1row = [&](int gg) -> int {
        if (sec == 0) return gg;                       // UB
        if (sec == 2) return OFF2 - GB_BASE + gg;      // BI
        return OFF1 + ((gg < NU) ? gg : gg - NB);      // UI
    };
    int deg = cnt[r]; if (deg > CAP) deg = CAP;
    const unsigned* ce = cv + (size_t)r * CAP;
    float a[8];
#pragma unroll
    for (int k = 0; k < 8; ++k) a[k] = 0.f;
    int j = 0;
    for (; j + 3 < deg; j += 4) {
        int c[4]; float v[4]; uint4 u[4];
#pragma unroll
        for (int k = 0; k < 4; ++k) edge_decode(ce[j + k], c[k], v[k]);
#pragma unroll
        for (int k = 0; k < 4; ++k)
            u[k] = *(const uint4*)(y1 + (((size_t)y1row(c[k])) << 6) + t * 8);
#pragma unroll
        for (int k = 0; k < 4; ++k) {
            a[0] = fmaf(v[k], bflo(u[k].x), a[0]); a[1] = fmaf(v[k], bfhi(u[k].x), a[1]);
            a[2] = fmaf(v[k], bflo(u[k].y), a[2]); a[3] = fmaf(v[k], bfhi(u[k].y), a[3]);
            a[4] = fmaf(v[k], bflo(u[k].z), a[4]); a[5] = fmaf(v[k], bfhi(u[k].z), a[5]);
            a[6] = fmaf(v[k], bflo(u[k].w), a[6]); a[7] = fmaf(v[k], bfhi(u[k].w), a[7]);
        }
    }
    for (; j < deg; ++j) {
        int c0; float v0;
        edge_decode(ce[j], c0, v0);
        uint4 u0 = *(const uint4*)(y1 + (((size_t)y1row(c0)) << 6) + t * 8);
        a[0] = fmaf(v0, bflo(u0.x), a[0]); a[1] = fmaf(v0, bfhi(u0.x), a[1]);
        a[2] = fmaf(v0, bflo(u0.y), a[2]); a[3] = fmaf(v0, bfhi(u0.y), a[3]);
        a[4] = fmaf(v0, bflo(u0.z), a[4]); a[5] = fmaf(v0, bfhi(u0.z), a[5]);
        a[6] = fmaf(v0, bflo(u0.w), a[6]); a[7] = fmaf(v0, bfhi(u0.w), a[7]);
    }
    uint4 fx = *(const uint4*)(gt + ((size_t)g << 6) + t * 8);   // original feature
    uint4 yx = *(const uint4*)(y1 + ((size_t)r << 6) + t * 8);
    constexpr float k3 = 1.0f / 3.0f;
    float o[8];
    o[0] = (bflo(fx.x) + bflo(yx.x) + a[0]) * k3;
    o[1] = (bfhi(fx.x) + bfhi(yx.x) + a[1]) * k3;
    o[2] = (bflo(fx.y) + bflo(yx.y) + a[2]) * k3;
    o[3] = (bfhi(fx.y) + bfhi(yx.y) + a[3]) * k3;
    o[4] = (bflo(fx.z) + bflo(yx.z) + a[4]) * k3;
    o[5] = (bfhi(fx.z) + bfhi(yx.z) + a[5]) * k3;
    o[6] = (bflo(fx.w) + bflo(yx.w) + a[6]) * k3;
    o[7] = (bfhi(fx.w) + bfhi(yx.w) + a[7]) * k3;
    uint4 w;
    w.x = pack2(o[0], o[1]); w.y = pack2(o[2], o[3]);
    w.z = pack2(o[4], o[5]); w.w = pack2(o[6], o[7]);
    *(uint4*)(xc + ((size_t)s << 6) + t * 8) = w;
}

// ---------------- K5: scoring + fused BPR loss (R18, kept) ----------------
__global__ __launch_bounds__(256) void k_score(
    const int* __restrict__ bundles,
    const int* __restrict__ bundle_items,
    const unsigned short* __restrict__ xc,
    const float* __restrict__ cw1, const float* __restrict__ cb1,
    const float* __restrict__ cw2, const float* __restrict__ cb2,
    const float* __restrict__ sw1, const float* __restrict__ sb1,
    const float* __restrict__ sw2, const float* __restrict__ sb2,
    float* __restrict__ accum, unsigned* __restrict__ tick,
    float* __restrict__ out) {
    const int t  = threadIdx.x;
    const int wv = t >> 6;               // wave 0..3 -> candidate
    const int ln = t & 63;
    const int n  = blockIdx.x * 4 + wv;  // grid = BATCH*NCAND/4
    const int g8 = ln >> 3;              // item subgroup (8 items in flight)
    const int l8 = ln & 7;               // feature octet within item
    const int uq = n >> 1;               // batch index
    const int b = bundles[n];

    __shared__ unsigned sh_it[4][MAXDEG][32];  // items_ui bf16: 50 x 64 (25.6 KB)
    __shared__ float sh_r[4][2][MAXDEG];       // dual dot results
    __shared__ float sh_syn[4][2 * D];         // [hcore | hfringe]
    __shared__ float sh_h1[4][D];              // relu(syn @ sw1 + sb1)
    __shared__ float sh_sc[4];                 // per-wave final scores

    int my_idx = (ln < MAXDEG) ? bundle_items[(size_t)b * MAXDEG + ln] : PAD_IDX;
    unsigned long long vmask = __ballot(my_idx != PAD_IDX);

    uint4 ufr = *(const uint4*)(xc + (((size_t)(S_UIU + uq)) << 6) + l8 * 8);
    uint4 bfr = *(const uint4*)(xc + (((size_t)(S_BIB + n)) << 6) + l8 * 8);
    float uf0 = bflo(ufr.x), uf1 = bfhi(ufr.x), uf2 = bflo(ufr.y), uf3 = bfhi(ufr.y);
    float uf4 = bflo(ufr.z), uf5 = bfhi(ufr.z), uf6 = bflo(ufr.w), uf7 = bfhi(ufr.w);
    float bf0 = bflo(bfr.x), bf1_ = bfhi(bfr.x), bf2 = bflo(bfr.y), bf3 = bfhi(bfr.y);
    float bf4 = bflo(bfr.z), bf5 = bfhi(bfr.z), bf6 = bflo(bfr.w), bf7 = bfhi(bfr.w);

    // --- P1: 50 dual dots, 8 items in flight x 8 lanes x 8 features ---
    for (int iter = 0; iter < (MAXDEG + 7) / 8; ++iter) {
        int m = iter * 8 + g8;
        if (m >= MAXDEG) continue;
        int it = __shfl(my_idx, m);
        uint4 iu = make_uint4(0, 0, 0, 0);
        float pu = 0.f, pb = 0.f;
        if (it != PAD_IDX) {
            iu = *(const uint4*)(xc + (((size_t)it) << 6) + l8 * 8);              // UI item
            uint4 ib = *(const uint4*)(xc + (((size_t)(NI + it)) << 6) + l8 * 8); // BI item
            pu = uf0 * bflo(iu.x) + uf1 * bfhi(iu.x) + uf2 * bflo(iu.y) + uf3 * bfhi(iu.y)
               + uf4 * bflo(iu.z) + uf5 * bfhi(iu.z) + uf6 * bflo(iu.w) + uf7 * bfhi(iu.w);
            pb = bf0 * bflo(ib.x) + bf1_ * bfhi(ib.x) + bf2 * bflo(ib.y) + bf3 * bfhi(ib.y)
               + bf4 * bflo(ib.z) + bf5 * bfhi(ib.z) + bf6 * bflo(ib.w) + bf7 * bfhi(ib.w);
        }
        *(uint4*)&sh_it[wv][m][l8 * 4] = iu;   // pads stash zeros
#pragma unroll
        for (int off = 4; off > 0; off >>= 1) {
            pu += __shfl_down(pu, off, 8);
            pb += __shfl_down(pb, off, 8);
        }
        if (l8 == 0) { sh_r[wv][0][m] = pu; sh_r[wv][1][m] = pb; }
    }
    __builtin_amdgcn_wave_barrier();

    // --- P2: core MLP (2->32->1), lane m = item m ---
    float logit = -INFINITY;
    if (ln < MAXDEG && my_idx != PAD_IDX) {
        float rU = sh_r[wv][0][ln], rB = sh_r[wv][1][ln];
        float acc = cb2[0];
#pragma unroll
        for (int j = 0; j < 32; ++j) {
            float h = fmaf(rU, cw1[j], fmaf(rB, cw1[32 + j], cb1[j]));
            h = fmaxf(h, 0.f);
            acc = fmaf(h, cw2[j], acc);
        }
        logit = acc;
    }

    // --- P3: wave-parallel softmax + top-3 ---
    float mx = logit;
#pragma unroll
    for (int off = 32; off > 0; off >>= 1) mx = fmaxf(mx, __shfl_xor(mx, off));
    float e = expf(logit - mx);            // pad lanes: exp(-inf)=0
    float sm = e;
#pragma unroll
    for (int off = 32; off > 0; off >>= 1) sm += __shfl_xor(sm, off);
    float p = e / sm;

    int ti[CORE_K]; float tp[CORE_K];
    float vsel = p;
#pragma unroll
    for (int k = 0; k < CORE_K; ++k) {
        float vv = vsel; int ii = ln;
#pragma unroll
        for (int off = 32; off > 0; off >>= 1) {
            float v2 = __shfl_xor(vv, off);
            int   i2 = __shfl_xor(ii, off);
            if (v2 > vv || (v2 == vv && i2 < ii)) { vv = v2; ii = i2; }
        }
        ti[k] = ii; tp[k] = vv;            // uniform across wave
        if (ln == ii) vsel = -1.f;
    }
    float tinv = 1.f / (tp[0] + tp[1] + tp[2] + 1e-10f);
    tp[0] *= tinv; tp[1] *= tinv; tp[2] *= tinv;

    // --- P4: h_core / h_fringe, lane = feature dim ---
    int ti0 = ti[0], ti1 = ti[1], ti2 = ti[2];
    const int ui_w = ln >> 1;
    const bool hi = (ln & 1);
    auto feat = [&](int m) -> float {
        unsigned w = sh_it[wv][m][ui_w];
        return hi ? bfhi(w) : bflo(w);
    };
    float hcore = feat(ti0) * tp[0] + feat(ti1) * tp[1] + feat(ti2) * tp[2];
    float fsum = 0.f;
#pragma unroll 10
    for (int m = 0; m < MAXDEG; ++m) fsum += feat(m);   // pads contribute 0
    int fcnt = __popcll(vmask);
#pragma unroll
    for (int k = 0; k < CORE_K; ++k) {
        if ((vmask >> ti[k]) & 1ull) { fsum -= feat(ti[k]); fcnt--; }
    }
    float hfr = fsum / fmaxf((float)fcnt, 1.f);
    sh_syn[wv][ln] = hcore;
    sh_syn[wv][D + ln] = hfr;
    __builtin_amdgcn_wave_barrier();

    // --- P5: synergy MLP (128->64 relu ->64), whole wave, LDS broadcast ---
    float h1 = sb1[ln];
#pragma unroll 8
    for (int k0 = 0; k0 < 32; ++k0) {
        float4 s4 = *(const float4*)&sh_syn[wv][k0 * 4];
        h1 = fmaf(s4.x, sw1[(k0 * 4 + 0) * D + ln], h1);
        h1 = fmaf(s4.y, sw1[(k0 * 4 + 1) * D + ln], h1);
        h1 = fmaf(s4.z, sw1[(k0 * 4 + 2) * D + ln], h1);
        h1 = fmaf(s4.w, sw1[(k0 * 4 + 3) * D + ln], h1);
    }
    sh_h1[wv][ln] = fmaxf(h1, 0.f);
    __builtin_amdgcn_wave_barrier();
    float phi = sb2[ln];
#pragma unroll 8
    for (int k0 = 0; k0 < 16; ++k0) {
        float4 s4 = *(const float4*)&sh_h1[wv][k0 * 4];
        phi = fmaf(s4.x, sw2[(k0 * 4 + 0) * D + ln], phi);
        phi = fmaf(s4.y, sw2[(k0 * 4 + 1) * D + ln], phi);
        phi = fmaf(s4.z, sw2[(k0 * 4 + 2) * D + ln], phi);
        phi = fmaf(s4.w, sw2[(k0 * 4 + 3) * D + ln], phi);
    }

    // --- P6: final score ---
    float hat = hcore + phi;
    float uui = bf1(xc + (((size_t)(S_UIU + uq)) << 6) + ln);
    float ubu = bf1(xc + (((size_t)(S_UBU + uq)) << 6) + ln);
    float ubb = bf1(xc + (((size_t)(S_UBB + n)) << 6) + ln);
    float part = wave_sum64(uui * ubb + ubu * hat);
    if (ln == 0) sh_sc[wv] = part;

    // --- fused BPR loss tail: pairs (wv 0,1) and (wv 2,3) ---
    __syncthreads();
    if (t == 0) {
        float x01 = sh_sc[1] - sh_sc[0];
        float x23 = sh_sc[3] - sh_sc[2];
        float spv = fmaxf(x01, 0.f) + log1pf(expf(-fabsf(x01)))
                  + fmaxf(x23, 0.f) + log1pf(expf(-fabsf(x23)));
        atomicAdd(accum, spv * (1.0f / (float)BATCH));
        __threadfence();
        unsigned old = atomicAdd(tick, 1u);
        if (old == gridDim.x - 1) {          // last block: publish
            __threadfence();
            float total = atomicAdd(accum, 0.0f);   // coherent RMW read
            out[0] = total;
        }
    }
}

extern "C" void kernel_launch(void* const* d_in, const int* in_sizes, int n_in,
                              void* d_out, int out_size, void* d_ws, size_t ws_size,
                              hipStream_t stream) {
    const float* users_feature   = (const float*)d_in[0];
    const float* bundles_feature = (const float*)d_in[1];
    const float* items_feature   = (const float*)d_in[2];
    const float* cw1 = (const float*)d_in[3];
    const float* cb1 = (const float*)d_in[4];
    const float* cw2 = (const float*)d_in[5];
    const float* cb2 = (const float*)d_in[6];
    const float* sw1 = (const float*)d_in[7];
    const float* sb1 = (const float*)d_in[8];
    const float* sw2 = (const float*)d_in[9];
    const float* sb2 = (const float*)d_in[10];
    const float* ub_val = (const float*)d_in[11];
    const float* ui_val = (const float*)d_in[12];
    const float* bi_val = (const float*)d_in[13];
    const int* users   = (const int*)d_in[14];
    const int* bundles = (const int*)d_in[15];
    const int* ub_row = (const int*)d_in[16];
    const int* ub_col = (const int*)d_in[17];
    const int* ui_row = (const int*)d_in[18];
    const int* ui_col = (const int*)d_in[19];
    const int* bi_row = (const int*)d_in[20];
    const int* bi_col = (const int*)d_in[21];
    const int* bundle_items = (const int*)d_in[22];
    const int E_UB = in_sizes[11], E_UI = in_sizes[12], E_BI = in_sizes[13];
    const int E_TOT = E_UB + E_UI + E_BI;

    // workspace layout (4-byte units), ~163 MB (< ~167 MB proven in R1)
    float* ws = (float*)d_ws;
    size_t off = 0;
    unsigned short* gt  = (unsigned short*)(ws + off); off += (size_t)NGF * 32;      // 21.8 MB
    unsigned short* y1b = (unsigned short*)(ws + off); off += (size_t)N_TOT * 32;    // 43.5 MB
    unsigned* cv  = (unsigned*)(ws + off); off += (size_t)N_TOT * CAP;               // 65.3 MB
    // stage (32.7 MB) overlays xc (27.2 MB): stage dead after k_bin2,
    // xc written only by k_spmm_l2 (later kernel).
    uint2* stage = (uint2*)(ws + off);
    unsigned short* xc = (unsigned short*)(ws + off);
    off += (size_t)NBUCK * BCAP * 2;                                                 // 32.7 MB
    // memset region: [bcnt | tick | accum | fS | f1 | f2 | du | db]
    int*   bcnt   = (int*)(ws + off); off += NBUCK;
    unsigned* tick = (unsigned*)(ws + off); off += 1;
    float* accum  = (float*)(ws + off); off += 1;
    unsigned char* fS = (unsigned char*)(ws + off); off += NI / 4;
    unsigned char* f1 = (unsigned char*)(ws + off); off += NI / 4;
    unsigned char* f2 = (unsigned char*)(ws + off); off += NI / 4;
    unsigned char* du = (unsigned char*)(ws + off); off += NU / 4;
    unsigned char* db = (unsigned char*)(ws + off); off += NB / 4;
    int*   cnt    = (int*)(ws + off); off += N_TOT;
    if (ws_size < off * sizeof(float)) return;  // fail loudly (wrong answer)

    // zero bcnt + tick + accum + flags (fS,f1,f2,du,db) in one memset
    hipMemsetAsync(bcnt, 0, (NBUCK + 2) * sizeof(int) + 3 * NI + NU + NB, stream);

    // K1: coarse binning + feature convert + demand seeds (merged; R26)
    const int nb1 = (E_TOT + P1_EPB - 1) / P1_EPB;
    const int ncvt = (int)(((size_t)NGF * 16 + 255) / 256);
    const int nb2 = nb1 + ncvt;
    const int nb3 = nb2 + MARK_A_BLOCKS;
    k_bin1cvt<<<nb3 + MARK_D_BLOCKS, P1_TPB, 0, stream>>>(
        ub_row, ub_col, ub_val, ui_row, ui_col, ui_val, bi_row, bi_col, bi_val,
        E_UB, E_UI, E_BI, nb1, nb2, nb3, bcnt, stage,
        users_feature, bundles_feature, items_feature, gt,
        users, bundles, bundle_items, fS, du, db);

    // K2: per-bucket refine + f1/f2 marking (k_mark folded in)
    k_bin2<<<NBUCK, 1024, 0, stream>>>(bcnt, stage, du, db, cnt, cv, f1, f2);

    // K3: demand-driven layer-1 gather
    k_spmm_l1<<<(N_TOT + 31) / 32, 256, 0, stream>>>(cnt, cv, gt, f1, f2, y1b);

    // K4: demand-driven layer 2 -> compact xc
    k_spmm_l2<<<(L2_SLOTS + 31) / 32, 256, 0, stream>>>(
        cnt, cv, users, bundles, y1b, gt, fS, xc);

    // K5: scoring + fused loss
    k_score<<<(BATCH * NCAND) / 4, 256, 0, stream>>>(
        bundles, bundle_items, xc,
        cw1, cb1, cw2, cb2, sw1, sb1, sw2, sb2,
        accum, tick, (float*)d_out);
}

// Round 14
// 323.048 us; speedup vs baseline: 1.0549x; 1.0194x over previous
//
#include <hip/hip_runtime.h>
#include <math.h>

// Problem constants (from reference)
constexpr int D = 64;
constexpr int NU = 50000, NB = 20000, NI = 100000;
constexpr int BATCH = 2048, NCAND = 2, MAXDEG = 50, CORE_K = 3;
constexpr int PAD_IDX = NI;
constexpr int N_UB = NU + NB, N_UI = NU + NI, N_BI = NB + NI;
constexpr int N_TOT = N_UB + N_UI + N_BI;   // 340000 combined node space
constexpr int OFF1 = N_UB;                  // UI node base
constexpr int OFF2 = N_UB + N_UI;           // BI node base
constexpr int CAP = 48;                     // fixed bucket capacity per row
constexpr float VAL_SCALE = 16383.0f / 0.2f;    // val in [0,0.2) -> 14-bit fixed
constexpr float VAL_INV   = 0.2f / 16383.0f;

// ---- global feature table (R17): dedup'd gather target ----
constexpr int GB_BASE = NU;            // 50000
constexpr int GI_BASE = NU + NB;       // 70000
constexpr int NGF = NU + NB + NI;      // 170000 (< 2^18, fits cv col field)

// ---- two-level binning (R14/R20/R23/R27) ----
// R27: 512-thread bin1 blocks (EPB 4096->8192). Phase-C write-run length
// per (block,bucket) = EPB/NBUCK: 3.1 edges -> 65us (R24), 6.2 -> 57us
// (R23/R26). Doubling to 12.3 (~98B runs) targets the partial-line scatter
// cost. LDS 69.3KB -> 2 blocks x 8 waves = 16 waves/CU (same occupancy as
// R26's 4 x 4) — isolates run length.
constexpr int BSHIFT = 9;
constexpr int BROWS  = 1 << BSHIFT;                      // 512 rows/bucket
constexpr int NBUCK  = (N_TOT + BROWS - 1) >> BSHIFT;    // 665
constexpr int BCAP   = 6144;     // bucket mean ~4510, sigma ~67 -> 24 sigma margin
constexpr int P1_EPT = 16;       // edges per thread in pass 1
constexpr int P1_TPB = 512;      // R27: 512 threads
constexpr int P1_EPB = P1_EPT * P1_TPB;                  // 8192 edges/block

// ---- demand-driven layer 2 (R16) + compact slot-indexed output (R17) ----
constexpr int L2_NCB = BATCH * NCAND;                    // 4096 candidate bundles
constexpr int L2_SLOTS = 2 * NI + 2 * BATCH + 2 * L2_NCB;  // 212288
constexpr int S_UBU = 2 * NI;                // UB user slots
constexpr int S_UIU = 2 * NI + BATCH;        // UI user slots
constexpr int S_UBB = 2 * NI + 2 * BATCH;    // UB bundle slots
constexpr int S_BIB = S_UBB + L2_NCB;        // BI bundle slots

// ---- demand-driven layer 1 (R21/R24): flags ----
// fS[i]: item in some candidate bundle  (set in bin1cvt spare blocks)
// du[u]/db[b]: user/bundle is demanded  (set in bin1cvt spare blocks)
// f1[i]/f2[i]: item adjacent to demanded user/bundle (set in bin2 from LDS)
constexpr int MARK_A_BLOCKS = (L2_NCB * MAXDEG + P1_TPB - 1) / P1_TPB;   // 400
constexpr int MARK_D_BLOCKS = (BATCH + L2_NCB + P1_TPB - 1) / P1_TPB;    // 12

__device__ __forceinline__ float wave_sum64(float v) {
#pragma unroll
    for (int off = 32; off > 0; off >>= 1) v += __shfl_down(v, off);
    return v;  // valid in lane 0
}

// ---- bf16 via raw bit ops (no API surface; RNE pack, <<16 unpack) ----
__device__ __forceinline__ float bflo(unsigned u) { return __uint_as_float(u << 16); }
__device__ __forceinline__ float bfhi(unsigned u) { return __uint_as_float(u & 0xFFFF0000u); }
__device__ __forceinline__ unsigned short f2bf(float f) {
    unsigned u = __float_as_uint(f);
    u += 0x7FFF + ((u >> 16) & 1);      // round-nearest-even
    return (unsigned short)(u >> 16);
}
__device__ __forceinline__ unsigned pack2(float a, float b) {
    return (unsigned)f2bf(a) | ((unsigned)f2bf(b) << 16);
}
__device__ __forceinline__ float bf1(const unsigned short* p) {
    return __uint_as_float(((unsigned)*p) << 16);
}

__device__ __forceinline__ void edge_decode(unsigned u, int& col, float& v) {
    col = (int)(u & 0x3FFFFu);
    v = (float)(u >> 18) * VAL_INV;
}

// ---------------- K1: coarse binning + cvt + demand seeds (R26/R27) ---------
// block ranges: [0,nb1) bin1 | [nb1,nb2) cvt | [nb2,nb3) fS | [nb3,...) du/db
__global__ __launch_bounds__(512) void k_bin1cvt(
    const int* __restrict__ r0, const int* __restrict__ c0,
    const float* __restrict__ v0,
    const int* __restrict__ r1, const int* __restrict__ c1,
    const float* __restrict__ v1,
    const int* __restrict__ r2, const int* __restrict__ c2,
    const float* __restrict__ v2,
    int e0, int e1, int e2, int nb1, int nb2, int nb3,
    int* __restrict__ bcnt, uint2* __restrict__ stage,
    const float* __restrict__ uf, const float* __restrict__ bf,
    const float* __restrict__ itf, unsigned short* __restrict__ gt,
    const int* __restrict__ users, const int* __restrict__ bundles,
    const int* __restrict__ bundle_items,
    unsigned char* __restrict__ fS, unsigned char* __restrict__ du,
    unsigned char* __restrict__ db) {
    const int t = threadIdx.x;
    const int bid = (int)blockIdx.x;
    if (bid >= nb3) {
        // ---- du/db: demanded user/bundle row seeds ----
        int q = (bid - nb3) * P1_TPB + t;
        if (q < BATCH) du[users[q]] = 1;
        else if (q < BATCH + L2_NCB) db[bundles[q - BATCH]] = 1;
        return;
    }
    if (bid >= nb2) {
        // ---- fS: items in candidate bundles ----
        int i = (bid - nb2) * P1_TPB + t;
        if (i < L2_NCB * MAXDEG) {
            int it = bundle_items[(size_t)bundles[i / MAXDEG] * MAXDEG + (i % MAXDEG)];
            if (it != PAD_IDX) fS[it] = 1;
        }
        return;
    }
    if (bid >= nb1) {
        // ---- cvt part ----
        size_t i = (size_t)(bid - nb1) * P1_TPB + t;   // 4-element group
        if (i >= (size_t)NGF * 16) return;
        int row = (int)(i >> 4);
        int q = ((int)i & 15) * 4;
        const float* src;
        if (row < GB_BASE)      src = uf  + (size_t)row * D;
        else if (row < GI_BASE) src = bf  + (size_t)(row - GB_BASE) * D;
        else                    src = itf + (size_t)(row - GI_BASE) * D;
        float4 v = *(const float4*)(src + q);
        ushort4 o;
        o.x = f2bf(v.x); o.y = f2bf(v.y); o.z = f2bf(v.z); o.w = f2bf(v.w);
        *(ushort4*)(gt + (size_t)row * D + q) = o;
        return;
    }
    // ---- bin1 part (R23 LDS-staged; R27 512-thread / 8192-edge blocks) ----
    __shared__ int s_hist[NBUCK];        // 2.7 KB
    __shared__ unsigned s_base[NBUCK];   // 2.7 KB
    __shared__ uint2 s_ed[P1_EPB];       // 64 KB edge staging
    const int etot = e0 + e1 + e2;
    const int i0 = bid * P1_EPB + t;
    for (int l = t; l < NBUCK; l += P1_TPB) s_hist[l] = 0;
    __syncthreads();
    // phase A: single edge read; hist atomic; stash {payload, r|lo<<19} in LDS
#pragma unroll
    for (int k = 0; k < P1_EPT; ++k) {
        int i = i0 + k * P1_TPB;
        uint2 ed = make_uint2(0u, 0xFFFFFFFFu);
        if (i < etot) {
            int r, g; float v;
            if (i < e0)           { r = r0[i]; g = c0[i]; v = v0[i]; }
            else if (i < e0 + e1) { int j = i - e0; r = r1[j] + OFF1;
                                    int c = c1[j]; g = (c < NU) ? c : c + NB; v = v1[j]; }
            else                  { int j = i - e0 - e1; r = r2[j] + OFF2;
                                    g = c2[j] + NU; v = v2[j]; }
            unsigned q = (unsigned)fminf(v * VAL_SCALE + 0.5f, 16383.0f);
            int lo = atomicAdd(&s_hist[r >> BSHIFT], 1);   // LDS atomic
            ed = make_uint2((q << 18) | (unsigned)g,
                            (unsigned)r | ((unsigned)lo << 19));  // r:19b, lo:13b
        }
        s_ed[k * P1_TPB + t] = ed;       // coalesced LDS store
    }
    __syncthreads();
    // phase B: reserve global runs
    for (int l = t; l < NBUCK; l += P1_TPB)
        s_base[l] = (unsigned)atomicAdd(&bcnt[l], s_hist[l]);
    __syncthreads();
    // phase C: replay from LDS; tight scatter loop
#pragma unroll
    for (int k = 0; k < P1_EPT; ++k) {
        uint2 e = s_ed[k * P1_TPB + t];
        if (e.y == 0xFFFFFFFFu) continue;
        unsigned r = e.y & 0x7FFFFu;
        unsigned b = r >> BSHIFT;
        unsigned slot = s_base[b] + (e.y >> 19);
        if (slot < (unsigned)BCAP)
            stage[(size_t)b * BCAP + slot] = make_uint2(e.x, r);
    }
}

// ---------------- K2: bucket refine + f1/f2 marking (R20/R24) ---------------
__global__ __launch_bounds__(1024) void k_bin2(
    const int* __restrict__ bcnt, const uint2* __restrict__ stage,
    const unsigned char* __restrict__ du, const unsigned char* __restrict__ db,
    int* __restrict__ cnt, unsigned* __restrict__ cv,
    unsigned char* __restrict__ f1, unsigned char* __restrict__ f2) {
    __shared__ unsigned lcv[BROWS][CAP];   // 96 KB
    __shared__ int s_c[BROWS];             // 2 KB
    const int b = blockIdx.x;
    const int t = threadIdx.x;
    if (t < BROWS) s_c[t] = 0;
    __syncthreads();
    int nb = bcnt[b]; if (nb > BCAP) nb = BCAP;
    const uint2* sp = stage + (size_t)b * BCAP;
    const int rbase = b << BSHIFT;
    for (int i = t; i < nb; i += 1024) {
        uint2 e = sp[i];
        int rl = (int)e.y - rbase;
        int slot = atomicAdd(&s_c[rl], 1);   // LDS atomic
        if (slot < CAP) lcv[rl][slot] = e.x;
    }
    __syncthreads();
    if (t < BROWS && rbase + t < N_TOT) cnt[rbase + t] = s_c[t];
    // f1/f2 marking for demanded UI-user / BI-bundle rows (LDS scan)
    if (t < BROWS) {
        int r = rbase + t;
        unsigned char* f = nullptr;
        if (r >= OFF1 && r < OFF1 + NU)      { if (du[r - OFF1]) f = f1; }
        else if (r >= OFF2 && r < OFF2 + NB) { if (db[r - OFF2]) f = f2; }
        if (f) {
            int deg = s_c[t]; if (deg > CAP) deg = CAP;
            for (int j = 0; j < deg; ++j) {
                int g = (int)(lcv[t][j] & 0x3FFFFu);
                if (g >= GI_BASE) f[g - GI_BASE] = 1;
            }
        }
    }
    // phase B: 64 groups of 16 lanes; group g writes rows g, g+64, ...
    const int g16 = t >> 4;
    const int l16 = t & 15;
#pragma unroll 1
    for (int rl = g16; rl < BROWS; rl += 64) {
        int r = rbase + rl;
        if (r >= N_TOT) continue;
        int deg = s_c[rl]; if (deg > CAP) deg = CAP;
        if (deg == 0) continue;
        int nwords = (deg + 15) & ~15;      // round up to 64B line
        if (l16 * 4 < nwords) {
            uint4 w = *(const uint4*)&lcv[rl][l16 * 4];
            *(uint4*)(cv + (size_t)r * CAP + l16 * 4) = w;
        }
    }
}

// ---------------- K3: layer 1, DEMAND-DRIVEN (R21) --------------------------
__global__ __launch_bounds__(256) void k_spmm_l1(
    const int* __restrict__ cnt, const unsigned* __restrict__ cv,
    const unsigned short* __restrict__ gt,
    const unsigned char* __restrict__ f1, const unsigned char* __restrict__ f2,
    unsigned short* __restrict__ y1) {
    int r = blockIdx.x * 32 + (threadIdx.x >> 3);
    int t = threadIdx.x & 7;            // 8 bf16 features per lane
    if (r >= N_TOT) return;
    // item-row demand check (user/bundle rows always needed)
    if (r >= OFF1 + NU && r < OFF2) { if (!f1[r - OFF1 - NU]) return; }
    else if (r >= OFF2 + NB)        { if (!f2[r - OFF2 - NB]) return; }
    int deg = cnt[r]; if (deg > CAP) deg = CAP;
    const unsigned* ce = cv + (size_t)r * CAP;
    float a[8];
#pragma unroll
    for (int k = 0; k < 8; ++k) a[k] = 0.f;
    int j = 0;
    for (; j + 3 < deg; j += 4) {
        int c[4]; float v[4]; uint4 u[4];
#pragma unroll
        for (int k = 0; k < 4; ++k) edge_decode(ce[j + k], c[k], v[k]);
#pragma unroll
        for (int k = 0; k < 4; ++k)
            u[k] = *(const uint4*)(gt + (((size_t)c[k]) << 6) + t * 8);
#pragma unroll
        for (int k = 0; k < 4; ++k) {
            a[0] = fmaf(v[k], bflo(u[k].x), a[0]); a[1] = fmaf(v[k], bfhi(u[k].x), a[1]);
            a[2] = fmaf(v[k], bflo(u[k].y), a[2]); a[3] = fmaf(v[k], bfhi(u[k].y), a[3]);
            a[4] = fmaf(v[k], bflo(u[k].z), a[4]); a[5] = fmaf(v[k], bfhi(u[k].z), a[5]);
            a[6] = fmaf(v[k], bflo(u[k].w), a[6]); a[7] = fmaf(v[k], bfhi(u[k].w), a[7]);
        }
    }
    for (; j < deg; ++j) {
        int c0; float v0;
        edge_decode(ce[j], c0, v0);
        uint4 u0 = *(const uint4*)(gt + (((size_t)c0) << 6) + t * 8);
        a[0] = fmaf(v0, bflo(u0.x), a[0]); a[1] = fmaf(v0, bfhi(u0.x), a[1]);
        a[2] = fmaf(v0, bflo(u0.y), a[2]); a[3] = fmaf(v0, bfhi(u0.y), a[3]);
        a[4] = fmaf(v0, bflo(u0.z), a[4]); a[5] = fmaf(v0, bfhi(u0.z), a[5]);
        a[6] = fmaf(v0, bflo(u0.w), a[6]); a[7] = fmaf(v0, bfhi(u0.w), a[7]);
    }
    uint4 o;
    o.x = pack2(a[0], a[1]); o.y = pack2(a[2], a[3]);
    o.z = pack2(a[4], a[5]); o.w = pack2(a[6], a[7]);
    *(uint4*)(y1 + ((size_t)r << 6) + t * 8) = o;
}

// ---------------- K4: layer 2 + mean, demand-driven, compact output --------
__global__ __launch_bounds__(256) void k_spmm_l2(
    const int* __restrict__ cnt, const unsigned* __restrict__ cv,
    const int* __restrict__ users, const int* __restrict__ bundles,
    const unsigned short* __restrict__ y1, const unsigned short* __restrict__ gt,
    const unsigned char* __restrict__ fS,
    unsigned short* __restrict__ xc) {
    int s = blockIdx.x * 32 + (threadIdx.x >> 3);
    int t = threadIdx.x & 7;
    if (s >= L2_SLOTS) return;
    int r, g, sec;
    if (s < NI)                { if (!fS[s]) return;                   // R21
                                 r = OFF1 + NU + s;        g = GI_BASE + s;        sec = 1; }
    else if (s < 2 * NI)       { int i = s - NI; if (!fS[i]) return;   // R21
                                 r = OFF2 + NB + i;        g = GI_BASE + i;        sec = 2; }
    else {
        int q = s - 2 * NI;
        if (q < BATCH)            { int u = users[q];             r = u;         g = u;            sec = 0; }
        else if (q < 2 * BATCH)   { int u = users[q - BATCH];     r = OFF1 + u;  g = u;            sec = 1; }
        else if (q < S_BIB - 2 * NI) { int b = bundles[q - 2 * BATCH];
                                    r = NU + b;    g = GB_BASE + b;  sec = 0; }
        else                      { int b = bundles[q - (S_BIB - 2 * NI)];
                                    r = OFF2 + b;  g = GB_BASE + b;  sec = 2; }
    }
    // inverse map: global feature idx -> y1 row in this section
    auto y1row = [&](int gg) -> int {
        if (sec == 0) return gg;                       // UB
        if (sec == 2) return OFF2 - GB_BASE + gg;      // BI
        return OFF1 + ((gg < NU) ? gg : gg - NB);      // UI
    };
    int deg = cnt[r]; if (deg > CAP) deg = CAP;
    const unsigned* ce = cv + (size_t)r * CAP;
    float a[8];
#pragma unroll
    for (int k = 0; k < 8; ++k) a[k] = 0.f;
    int j = 0;
    for (; j + 3 < deg; j += 4) {
        int c[4]; float v[4]; uint4 u[4];
#pragma unroll
        for (int k = 0; k < 4; ++k) edge_decode(ce[j + k], c[k], v[k]);
#pragma unroll
        for (int k = 0; k < 4; ++k)
            u[k] = *(const uint4*)(y1 + (((size_t)y1row(c[k])) << 6) + t * 8);
#pragma unroll
        for (int k = 0; k < 4; ++k) {
            a[0] = fmaf(v[k], bflo(u[k].x), a[0]); a[1] = fmaf(v[k], bfhi(u[k].x), a[1]);
            a[2] = fmaf(v[k], bflo(u[k].y), a[2]); a[3] = fmaf(v[k], bfhi(u[k].y), a[3]);
            a[4] = fmaf(v[k], bflo(u[k].z), a[4]); a[5] = fmaf(v[k], bfhi(u[k].z), a[5]);
            a[6] = fmaf(v[k], bflo(u[k].w), a[6]); a[7] = fmaf(v[k], bfhi(u[k].w), a[7]);
        }
    }
    for (; j < deg; ++j) {
        int c0; float v0;
        edge_decode(ce[j], c0, v0);
        uint4 u0 = *(const uint4*)(y1 + (((size_t)y1row(c0)) << 6) + t * 8);
        a[0] = fmaf(v0, bflo(u0.x), a[0]); a[1] = fmaf(v0, bfhi(u0.x), a[1]);
        a[2] = fmaf(v0, bflo(u0.y), a[2]); a[3] = fmaf(v0, bfhi(u0.y), a[3]);
        a[4] = fmaf(v0, bflo(u0.z), a[4]); a[5] = fmaf(v0, bfhi(u0.z), a[5]);
        a[6] = fmaf(v0, bflo(u0.w), a[6]); a[7] = fmaf(v0, bfhi(u0.w), a[7]);
    }
    uint4 fx = *(const uint4*)(gt + ((size_t)g << 6) + t * 8);   // original feature
    uint4 yx = *(const uint4*)(y1 + ((size_t)r << 6) + t * 8);
    constexpr float k3 = 1.0f / 3.0f;
    float o[8];
    o[0] = (bflo(fx.x) + bflo(yx.x) + a[0]) * k3;
    o[1] = (bfhi(fx.x) + bfhi(yx.x) + a[1]) * k3;
    o[2] = (bflo(fx.y) + bflo(yx.y) + a[2]) * k3;
    o[3] = (bfhi(fx.y) + bfhi(yx.y) + a[3]) * k3;
    o[4] = (bflo(fx.z) + bflo(yx.z) + a[4]) * k3;
    o[5] = (bfhi(fx.z) + bfhi(yx.z) + a[5]) * k3;
    o[6] = (bflo(fx.w) + bflo(yx.w) + a[6]) * k3;
    o[7] = (bfhi(fx.w) + bfhi(yx.w) + a[7]) * k3;
    uint4 w;
    w.x = pack2(o[0], o[1]); w.y = pack2(o[2], o[3]);
    w.z = pack2(o[4], o[5]); w.w = pack2(o[6], o[7]);
    *(uint4*)(xc + ((size_t)s << 6) + t * 8) = w;
}

// ---------------- K5: scoring + fused BPR loss (R18, kept) ----------------
__global__ __launch_bounds__(256) void k_score(
    const int* __restrict__ bundles,
    const int* __restrict__ bundle_items,
    const unsigned short* __restrict__ xc,
    const float* __restrict__ cw1, const float* __restrict__ cb1,
    const float* __restrict__ cw2, const float* __restrict__ cb2,
    const float* __restrict__ sw1, const float* __restrict__ sb1,
    const float* __restrict__ sw2, const float* __restrict__ sb2,
    float* __restrict__ accum, unsigned* __restrict__ tick,
    float* __restrict__ out) {
    const int t  = threadIdx.x;
    const int wv = t >> 6;               // wave 0..3 -> candidate
    const int ln = t & 63;
    const int n  = blockIdx.x * 4 + wv;  // grid = BATCH*NCAND/4
    const int g8 = ln >> 3;              // item subgroup (8 items in flight)
    const int l8 = ln & 7;               // feature octet within item
    const int uq = n >> 1;               // batch index
    const int b = bundles[n];

    __shared__ unsigned sh_it[4][MAXDEG][32];  // items_ui bf16: 50 x 64 (25.6 KB)
    __shared__ float sh_r[4][2][MAXDEG];       // dual dot results
    __shared__ float sh_syn[4][2 * D];         // [hcore | hfringe]
    __shared__ float sh_h1[4][D];              // relu(syn @ sw1 + sb1)
    __shared__ float sh_sc[4];                 // per-wave final scores

    int my_idx = (ln < MAXDEG) ? bundle_items[(size_t)b * MAXDEG + ln] : PAD_IDX;
    unsigned long long vmask = __ballot(my_idx != PAD_IDX);

    uint4 ufr = *(const uint4*)(xc + (((size_t)(S_UIU + uq)) << 6) + l8 * 8);
    uint4 bfr = *(const uint4*)(xc + (((size_t)(S_BIB + n)) << 6) + l8 * 8);
    float uf0 = bflo(ufr.x), uf1 = bfhi(ufr.x), uf2 = bflo(ufr.y), uf3 = bfhi(ufr.y);
    float uf4 = bflo(ufr.z), uf5 = bfhi(ufr.z), uf6 = bflo(ufr.w), uf7 = bfhi(ufr.w);
    float bf0 = bflo(bfr.x), bf1_ = bfhi(bfr.x), bf2 = bflo(bfr.y), bf3 = bfhi(bfr.y);
    float bf4 = bflo(bfr.z), bf5 = bfhi(bfr.z), bf6 = bflo(bfr.w), bf7 = bfhi(bfr.w);

    // --- P1: 50 dual dots, 8 items in flight x 8 lanes x 8 features ---
    for (int iter = 0; iter < (MAXDEG + 7) / 8; ++iter) {
        int m = iter * 8 + g8;
        if (m >= MAXDEG) continue;
        int it = __shfl(my_idx, m);
        uint4 iu = make_uint4(0, 0, 0, 0);
        float pu = 0.f, pb = 0.f;
        if (it != PAD_IDX) {
            iu = *(const uint4*)(xc + (((size_t)it) << 6) + l8 * 8);              // UI item
            uint4 ib = *(const uint4*)(xc + (((size_t)(NI + it)) << 6) + l8 * 8); // BI item
            pu = uf0 * bflo(iu.x) + uf1 * bfhi(iu.x) + uf2 * bflo(iu.y) + uf3 * bfhi(iu.y)
               + uf4 * bflo(iu.z) + uf5 * bfhi(iu.z) + uf6 * bflo(iu.w) + uf7 * bfhi(iu.w);
            pb = bf0 * bflo(ib.x) + bf1_ * bfhi(ib.x) + bf2 * bflo(ib.y) + bf3 * bfhi(ib.y)
               + bf4 * bflo(ib.z) + bf5 * bfhi(ib.z) + bf6 * bflo(ib.w) + bf7 * bfhi(ib.w);
        }
        *(uint4*)&sh_it[wv][m][l8 * 4] = iu;   // pads stash zeros
#pragma unroll
        for (int off = 4; off > 0; off >>= 1) {
            pu += __shfl_down(pu, off, 8);
            pb += __shfl_down(pb, off, 8);
        }
        if (l8 == 0) { sh_r[wv][0][m] = pu; sh_r[wv][1][m] = pb; }
    }
    __builtin_amdgcn_wave_barrier();

    // --- P2: core MLP (2->32->1), lane m = item m ---
    float logit = -INFINITY;
    if (ln < MAXDEG && my_idx != PAD_IDX) {
        float rU = sh_r[wv][0][ln], rB = sh_r[wv][1][ln];
        float acc = cb2[0];
#pragma unroll
        for (int j = 0; j < 32; ++j) {
            float h = fmaf(rU, cw1[j], fmaf(rB, cw1[32 + j], cb1[j]));
            h = fmaxf(h, 0.f);
            acc = fmaf(h, cw2[j], acc);
        }
        logit = acc;
    }

    // --- P3: wave-parallel softmax + top-3 ---
    float mx = logit;
#pragma unroll
    for (int off = 32; off > 0; off >>= 1) mx = fmaxf(mx, __shfl_xor(mx, off));
    float e = expf(logit - mx);            // pad lanes: exp(-inf)=0
    float sm = e;
#pragma unroll
    for (int off = 32; off > 0; off >>= 1) sm += __shfl_xor(sm, off);
    float p = e / sm;

    int ti[CORE_K]; float tp[CORE_K];
    float vsel = p;
#pragma unroll
    for (int k = 0; k < CORE_K; ++k) {
        float vv = vsel; int ii = ln;
#pragma unroll
        for (int off = 32; off > 0; off >>= 1) {
            float v2 = __shfl_xor(vv, off);
            int   i2 = __shfl_xor(ii, off);
            if (v2 > vv || (v2 == vv && i2 < ii)) { vv = v2; ii = i2; }
        }
        ti[k] = ii; tp[k] = vv;            // uniform across wave
        if (ln == ii) vsel = -1.f;
    }
    float tinv = 1.f / (tp[0] + tp[1] + tp[2] + 1e-10f);
    tp[0] *= tinv; tp[1] *= tinv; tp[2] *= tinv;

    // --- P4: h_core / h_fringe, lane = feature dim ---
    int ti0 = ti[0], ti1 = ti[1], ti2 = ti[2];
    const int ui_w = ln >> 1;
    const bool hi = (ln & 1);
    auto feat = [&](int m) -> float {
        unsigned w = sh_it[wv][m][ui_w];
        return hi ? bfhi(w) : bflo(w);
    };
    float hcore = feat(ti0) * tp[0] + feat(ti1) * tp[1] + feat(ti2) * tp[2];
    float fsum = 0.f;
#pragma unroll 10
    for (int m = 0; m < MAXDEG; ++m) fsum += feat(m);   // pads contribute 0
    int fcnt = __popcll(vmask);
#pragma unroll
    for (int k = 0; k < CORE_K; ++k) {
        if ((vmask >> ti[k]) & 1ull) { fsum -= feat(ti[k]); fcnt--; }
    }
    float hfr = fsum / fmaxf((float)fcnt, 1.f);
    sh_syn[wv][ln] = hcore;
    sh_syn[wv][D + ln] = hfr;
    __builtin_amdgcn_wave_barrier();

    // --- P5: synergy MLP (128->64 relu ->64), whole wave, LDS broadcast ---
    float h1 = sb1[ln];
#pragma unroll 8
    for (int k0 = 0; k0 < 32; ++k0) {
        float4 s4 = *(const float4*)&sh_syn[wv][k0 * 4];
        h1 = fmaf(s4.x, sw1[(k0 * 4 + 0) * D + ln], h1);
        h1 = fmaf(s4.y, sw1[(k0 * 4 + 1) * D + ln], h1);
        h1 = fmaf(s4.z, sw1[(k0 * 4 + 2) * D + ln], h1);
        h1 = fmaf(s4.w, sw1[(k0 * 4 + 3) * D + ln], h1);
    }
    sh_h1[wv][ln] = fmaxf(h1, 0.f);
    __builtin_amdgcn_wave_barrier();
    float phi = sb2[ln];
#pragma unroll 8
    for (int k0 = 0; k0 < 16; ++k0) {
        float4 s4 = *(const float4*)&sh_h1[wv][k0 * 4];
        phi = fmaf(s4.x, sw2[(k0 * 4 + 0) * D + ln], phi);
        phi = fmaf(s4.y, sw2[(k0 * 4 + 1) * D + ln], phi);
        phi = fmaf(s4.z, sw2[(k0 * 4 + 2) * D + ln], phi);
        phi = fmaf(s4.w, sw2[(k0 * 4 + 3) * D + ln], phi);
    }

    // --- P6: final score ---
    float hat = hcore + phi;
    float uui = bf1(xc + (((size_t)(S_UIU + uq)) << 6) + ln);
    float ubu = bf1(xc + (((size_t)(S_UBU + uq)) << 6) + ln);
    float ubb = bf1(xc + (((size_t)(S_UBB + n)) << 6) + ln);
    float part = wave_sum64(uui * ubb + ubu * hat);
    if (ln == 0) sh_sc[wv] = part;

    // --- fused BPR loss tail: pairs (wv 0,1) and (wv 2,3) ---
    __syncthreads();
    if (t == 0) {
        float x01 = sh_sc[1] - sh_sc[0];
        float x23 = sh_sc[3] - sh_sc[2];
        float spv = fmaxf(x01, 0.f) + log1pf(expf(-fabsf(x01)))
                  + fmaxf(x23, 0.f) + log1pf(expf(-fabsf(x23)));
        atomicAdd(accum, spv * (1.0f / (float)BATCH));
        __threadfence();
        unsigned old = atomicAdd(tick, 1u);
        if (old == gridDim.x - 1) {          // last block: publish
            __threadfence();
            float total = atomicAdd(accum, 0.0f);   // coherent RMW read
            out[0] = total;
        }
    }
}

extern "C" void kernel_launch(void* const* d_in, const int* in_sizes, int n_in,
                              void* d_out, int out_size, void* d_ws, size_t ws_size,
                              hipStream_t stream) {
    const float* users_feature   = (const float*)d_in[0];
    const float* bundles_feature = (const float*)d_in[1];
    const float* items_feature   = (const float*)d_in[2];
    const float* cw1 = (const float*)d_in[3];
    const float* cb1 = (const float*)d_in[4];
    const float* cw2 = (const float*)d_in[5];
    const float* cb2 = (const float*)d_in[6];
    const float* sw1 = (const float*)d_in[7];
    const float* sb1 = (const float*)d_in[8];
    const float* sw2 = (const float*)d_in[9];
    const float* sb2 = (const float*)d_in[10];
    const float* ub_val = (const float*)d_in[11];
    const float* ui_val = (const float*)d_in[12];
    const float* bi_val = (const float*)d_in[13];
    const int* users   = (const int*)d_in[14];
    const int* bundles = (const int*)d_in[15];
    const int* ub_row = (const int*)d_in[16];
    const int* ub_col = (const int*)d_in[17];
    const int* ui_row = (const int*)d_in[18];
    const int* ui_col = (const int*)d_in[19];
    const int* bi_row = (const int*)d_in[20];
    const int* bi_col = (const int*)d_in[21];
    const int* bundle_items = (const int*)d_in[22];
    const int E_UB = in_sizes[11], E_UI = in_sizes[12], E_BI = in_sizes[13];
    const int E_TOT = E_UB + E_UI + E_BI;

    // workspace layout (4-byte units), ~163 MB (< ~167 MB proven in R1)
    float* ws = (float*)d_ws;
    size_t off = 0;
    unsigned short* gt  = (unsigned short*)(ws + off); off += (size_t)NGF * 32;      // 21.8 MB
    unsigned short* y1b = (unsigned short*)(ws + off); off += (size_t)N_TOT * 32;    // 43.5 MB
    unsigned* cv  = (unsigned*)(ws + off); off += (size_t)N_TOT * CAP;               // 65.3 MB
    // stage (32.7 MB) overlays xc (27.2 MB): stage dead after k_bin2,
    // xc written only by k_spmm_l2 (later kernel).
    uint2* stage = (uint2*)(ws + off);
    unsigned short* xc = (unsigned short*)(ws + off);
    off += (size_t)NBUCK * BCAP * 2;                                                 // 32.7 MB
    // memset region: [bcnt | tick | accum | fS | f1 | f2 | du | db]
    int*   bcnt   = (int*)(ws + off); off += NBUCK;
    unsigned* tick = (unsigned*)(ws + off); off += 1;
    float* accum  = (float*)(ws + off); off += 1;
    unsigned char* fS = (unsigned char*)(ws + off); off += NI / 4;
    unsigned char* f1 = (unsigned char*)(ws + off); off += NI / 4;
    unsigned char* f2 = (unsigned char*)(ws + off); off += NI / 4;
    unsigned char* du = (unsigned char*)(ws + off); off += NU / 4;
    unsigned char* db = (unsigned char*)(ws + off); off += NB / 4;
    int*   cnt    = (int*)(ws + off); off += N_TOT;
    if (ws_size < off * sizeof(float)) return;  // fail loudly (wrong answer)

    // zero bcnt + tick + accum + flags (fS,f1,f2,du,db) in one memset
    hipMemsetAsync(bcnt, 0, (NBUCK + 2) * sizeof(int) + 3 * NI + NU + NB, stream);

    // K1: coarse binning + feature convert + demand seeds (merged; R27)
    const int nb1 = (E_TOT + P1_EPB - 1) / P1_EPB;
    const int ncvt = (int)(((size_t)NGF * 16 + P1_TPB - 1) / P1_TPB);
    const int nb2 = nb1 + ncvt;
    const int nb3 = nb2 + MARK_A_BLOCKS;
    k_bin1cvt<<<nb3 + MARK_D_BLOCKS, P1_TPB, 0, stream>>>(
        ub_row, ub_col, ub_val, ui_row, ui_col, ui_val, bi_row, bi_col, bi_val,
        E_UB, E_UI, E_BI, nb1, nb2, nb3, bcnt, stage,
        users_feature, bundles_feature, items_feature, gt,
        users, bundles, bundle_items, fS, du, db);

    // K2: per-bucket refine + f1/f2 marking (k_mark folded in)
    k_bin2<<<NBUCK, 1024, 0, stream>>>(bcnt, stage, du, db, cnt, cv, f1, f2);

    // K3: demand-driven layer-1 gather
    k_spmm_l1<<<(N_TOT + 31) / 32, 256, 0, stream>>>(cnt, cv, gt, f1, f2, y1b);

    // K4: demand-driven layer 2 -> compact xc
    k_spmm_l2<<<(L2_SLOTS + 31) / 32, 256, 0, stream>>>(
        cnt, cv, users, bundles, y1b, gt, fS, xc);

    // K5: scoring + fused loss
    k_score<<<(BATCH * NCAND) / 4, 256, 0, stream>>>(
        bundles, bundle_items, xc,
        cw1, cb1, cw2, cb2, sw1, sb1, sw2, sb2,
        accum, tick, (float*)d_out);
}

// Round 15
// 320.395 us; speedup vs baseline: 1.0636x; 1.0083x over previous
//
#include <hip/hip_runtime.h>
#include <math.h>

// Problem constants (from reference)
constexpr int D = 64;
constexpr int NU = 50000, NB = 20000, NI = 100000;
constexpr int BATCH = 2048, NCAND = 2, MAXDEG = 50, CORE_K = 3;
constexpr int PAD_IDX = NI;
constexpr int N_UB = NU + NB, N_UI = NU + NI, N_BI = NB + NI;
constexpr int N_TOT = N_UB + N_UI + N_BI;   // 340000 combined node space
constexpr int OFF1 = N_UB;                  // UI node base
constexpr int OFF2 = N_UB + N_UI;           // BI node base
constexpr int CAP = 48;                     // fixed bucket capacity per row
constexpr float VAL_SCALE = 16383.0f / 0.2f;    // val in [0,0.2) -> 14-bit fixed
constexpr float VAL_INV   = 0.2f / 16383.0f;

// ---- global feature table (R17): dedup'd gather target ----
constexpr int GB_BASE = NU;            // 50000
constexpr int GI_BASE = NU + NB;       // 70000
constexpr int NGF = NU + NB + NI;      // 170000 (< 2^18, fits cv col field)

// ---- two-level binning (R14/R20/R23/R27/R28) ----
// R28: TPB 512->1024 (EPB 8192->16384). Phase-C run length per
// (block,bucket): 3.1 edges -> 65us, 6.2 -> 57us, 12.3 -> 52us. Doubling to
// 24.6 (~197B runs, 3-4 full lines). LDS 133.3KB -> 1 block x 16 waves =
// 16 waves/CU — SAME occupancy as R27's 2 x 8 for every block type.
constexpr int BSHIFT = 9;
constexpr int BROWS  = 1 << BSHIFT;                      // 512 rows/bucket
constexpr int NBUCK  = (N_TOT + BROWS - 1) >> BSHIFT;    // 665
constexpr int BCAP   = 6144;     // bucket mean ~4510, sigma ~67 -> 24 sigma margin
constexpr int P1_EPT = 16;       // edges per thread in pass 1
constexpr int P1_TPB = 1024;     // R28: 1024 threads
constexpr int P1_EPB = P1_EPT * P1_TPB;                  // 16384 edges/block

// ---- demand-driven layer 2 (R16) + compact slot-indexed output (R17) ----
constexpr int L2_NCB = BATCH * NCAND;                    // 4096 candidate bundles
constexpr int L2_SLOTS = 2 * NI + 2 * BATCH + 2 * L2_NCB;  // 212288
constexpr int S_UBU = 2 * NI;                // UB user slots
constexpr int S_UIU = 2 * NI + BATCH;        // UI user slots
constexpr int S_UBB = 2 * NI + 2 * BATCH;    // UB bundle slots
constexpr int S_BIB = S_UBB + L2_NCB;        // BI bundle slots

// ---- demand-driven layer 1 (R21/R24): flags ----
// fS[i]: item in some candidate bundle  (set in bin1cvt spare blocks)
// du[u]/db[b]: user/bundle is demanded  (set in bin1cvt spare blocks)
// f1[i]/f2[i]: item adjacent to demanded user/bundle (set in bin2 from LDS)
constexpr int MARK_A_BLOCKS = (L2_NCB * MAXDEG + P1_TPB - 1) / P1_TPB;   // 200
constexpr int MARK_D_BLOCKS = (BATCH + L2_NCB + P1_TPB - 1) / P1_TPB;    // 6

__device__ __forceinline__ float wave_sum64(float v) {
#pragma unroll
    for (int off = 32; off > 0; off >>= 1) v += __shfl_down(v, off);
    return v;  // valid in lane 0
}

// ---- bf16 via raw bit ops (no API surface; RNE pack, <<16 unpack) ----
__device__ __forceinline__ float bflo(unsigned u) { return __uint_as_float(u << 16); }
__device__ __forceinline__ float bfhi(unsigned u) { return __uint_as_float(u & 0xFFFF0000u); }
__device__ __forceinline__ unsigned short f2bf(float f) {
    unsigned u = __float_as_uint(f);
    u += 0x7FFF + ((u >> 16) & 1);      // round-nearest-even
    return (unsigned short)(u >> 16);
}
__device__ __forceinline__ unsigned pack2(float a, float b) {
    return (unsigned)f2bf(a) | ((unsigned)f2bf(b) << 16);
}
__device__ __forceinline__ float bf1(const unsigned short* p) {
    return __uint_as_float(((unsigned)*p) << 16);
}

__device__ __forceinline__ void edge_decode(unsigned u, int& col, float& v) {
    col = (int)(u & 0x3FFFFu);
    v = (float)(u >> 18) * VAL_INV;
}

// ---------------- K1: coarse binning + cvt + demand seeds (R26/R28) ---------
// block ranges: [0,nb1) bin1 | [nb1,nb2) cvt | [nb2,nb3) fS | [nb3,...) du/db
__global__ __launch_bounds__(1024) void k_bin1cvt(
    const int* __restrict__ r0, const int* __restrict__ c0,
    const float* __restrict__ v0,
    const int* __restrict__ r1, const int* __restrict__ c1,
    const float* __restrict__ v1,
    const int* __restrict__ r2, const int* __restrict__ c2,
    const float* __restrict__ v2,
    int e0, int e1, int e2, int nb1, int nb2, int nb3,
    int* __restrict__ bcnt, uint2* __restrict__ stage,
    const float* __restrict__ uf, const float* __restrict__ bf,
    const float* __restrict__ itf, unsigned short* __restrict__ gt,
    const int* __restrict__ users, const int* __restrict__ bundles,
    const int* __restrict__ bundle_items,
    unsigned char* __restrict__ fS, unsigned char* __restrict__ du,
    unsigned char* __restrict__ db) {
    const int t = threadIdx.x;
    const int bid = (int)blockIdx.x;
    if (bid >= nb3) {
        // ---- du/db: demanded user/bundle row seeds ----
        int q = (bid - nb3) * P1_TPB + t;
        if (q < BATCH) du[users[q]] = 1;
        else if (q < BATCH + L2_NCB) db[bundles[q - BATCH]] = 1;
        return;
    }
    if (bid >= nb2) {
        // ---- fS: items in candidate bundles ----
        int i = (bid - nb2) * P1_TPB + t;
        if (i < L2_NCB * MAXDEG) {
            int it = bundle_items[(size_t)bundles[i / MAXDEG] * MAXDEG + (i % MAXDEG)];
            if (it != PAD_IDX) fS[it] = 1;
        }
        return;
    }
    if (bid >= nb1) {
        // ---- cvt part ----
        size_t i = (size_t)(bid - nb1) * P1_TPB + t;   // 4-element group
        if (i >= (size_t)NGF * 16) return;
        int row = (int)(i >> 4);
        int q = ((int)i & 15) * 4;
        const float* src;
        if (row < GB_BASE)      src = uf  + (size_t)row * D;
        else if (row < GI_BASE) src = bf  + (size_t)(row - GB_BASE) * D;
        else                    src = itf + (size_t)(row - GI_BASE) * D;
        float4 v = *(const float4*)(src + q);
        ushort4 o;
        o.x = f2bf(v.x); o.y = f2bf(v.y); o.z = f2bf(v.z); o.w = f2bf(v.w);
        *(ushort4*)(gt + (size_t)row * D + q) = o;
        return;
    }
    // ---- bin1 part (R23 LDS-staged; R28 1024-thread / 16384-edge blocks) ----
    __shared__ int s_hist[NBUCK];        // 2.7 KB
    __shared__ unsigned s_base[NBUCK];   // 2.7 KB
    __shared__ uint2 s_ed[P1_EPB];       // 128 KB edge staging
    const int etot = e0 + e1 + e2;
    const int i0 = bid * P1_EPB + t;
    if (t < NBUCK) s_hist[t] = 0;
    __syncthreads();
    // phase A: single edge read; hist atomic; stash {payload, r|lo<<19} in LDS
#pragma unroll
    for (int k = 0; k < P1_EPT; ++k) {
        int i = i0 + k * P1_TPB;
        uint2 ed = make_uint2(0u, 0xFFFFFFFFu);
        if (i < etot) {
            int r, g; float v;
            if (i < e0)           { r = r0[i]; g = c0[i]; v = v0[i]; }
            else if (i < e0 + e1) { int j = i - e0; r = r1[j] + OFF1;
                                    int c = c1[j]; g = (c < NU) ? c : c + NB; v = v1[j]; }
            else                  { int j = i - e0 - e1; r = r2[j] + OFF2;
                                    g = c2[j] + NU; v = v2[j]; }
            unsigned q = (unsigned)fminf(v * VAL_SCALE + 0.5f, 16383.0f);
            int lo = atomicAdd(&s_hist[r >> BSHIFT], 1);   // LDS atomic
            ed = make_uint2((q << 18) | (unsigned)g,
                            (unsigned)r | ((unsigned)lo << 19));  // r:19b, lo:13b
        }
        s_ed[k * P1_TPB + t] = ed;       // coalesced LDS store
    }
    __syncthreads();
    // phase B: reserve global runs
    if (t < NBUCK)
        s_base[t] = (unsigned)atomicAdd(&bcnt[t], s_hist[t]);
    __syncthreads();
    // phase C: replay from LDS; tight scatter loop
#pragma unroll
    for (int k = 0; k < P1_EPT; ++k) {
        uint2 e = s_ed[k * P1_TPB + t];
        if (e.y == 0xFFFFFFFFu) continue;
        unsigned r = e.y & 0x7FFFFu;
        unsigned b = r >> BSHIFT;
        unsigned slot = s_base[b] + (e.y >> 19);
        if (slot < (unsigned)BCAP)
            stage[(size_t)b * BCAP + slot] = make_uint2(e.x, r);
    }
}

// ---------------- K2: bucket refine + f1/f2 marking (R20/R24) ---------------
__global__ __launch_bounds__(1024) void k_bin2(
    const int* __restrict__ bcnt, const uint2* __restrict__ stage,
    const unsigned char* __restrict__ du, const unsigned char* __restrict__ db,
    int* __restrict__ cnt, unsigned* __restrict__ cv,
    unsigned char* __restrict__ f1, unsigned char* __restrict__ f2) {
    __shared__ unsigned lcv[BROWS][CAP];   // 96 KB
    __shared__ int s_c[BROWS];             // 2 KB
    const int b = blockIdx.x;
    const int t = threadIdx.x;
    if (t < BROWS) s_c[t] = 0;
    __syncthreads();
    int nb = bcnt[b]; if (nb > BCAP) nb = BCAP;
    const uint2* sp = stage + (size_t)b * BCAP;
    const int rbase = b << BSHIFT;
    for (int i = t; i < nb; i += 1024) {
        uint2 e = sp[i];
        int rl = (int)e.y - rbase;
        int slot = atomicAdd(&s_c[rl], 1);   // LDS atomic
        if (slot < CAP) lcv[rl][slot] = e.x;
    }
    __syncthreads();
    if (t < BROWS && rbase + t < N_TOT) cnt[rbase + t] = s_c[t];
    // f1/f2 marking for demanded UI-user / BI-bundle rows (LDS scan)
    if (t < BROWS) {
        int r = rbase + t;
        unsigned char* f = nullptr;
        if (r >= OFF1 && r < OFF1 + NU)      { if (du[r - OFF1]) f = f1; }
        else if (r >= OFF2 && r < OFF2 + NB) { if (db[r - OFF2]) f = f2; }
        if (f) {
            int deg = s_c[t]; if (deg > CAP) deg = CAP;
            for (int j = 0; j < deg; ++j) {
                int g = (int)(lcv[t][j] & 0x3FFFFu);
                if (g >= GI_BASE) f[g - GI_BASE] = 1;
            }
        }
    }
    // phase B: 64 groups of 16 lanes; group g writes rows g, g+64, ...
    const int g16 = t >> 4;
    const int l16 = t & 15;
#pragma unroll 1
    for (int rl = g16; rl < BROWS; rl += 64) {
        int r = rbase + rl;
        if (r >= N_TOT) continue;
        int deg = s_c[rl]; if (deg > CAP) deg = CAP;
        if (deg == 0) continue;
        int nwords = (deg + 15) & ~15;      // round up to 64B line
        if (l16 * 4 < nwords) {
            uint4 w = *(const uint4*)&lcv[rl][l16 * 4];
            *(uint4*)(cv + (size_t)r * CAP + l16 * 4) = w;
        }
    }
}

// ---------------- K3: layer 1, DEMAND-DRIVEN (R21) --------------------------
__global__ __launch_bounds__(256) void k_spmm_l1(
    const int* __restrict__ cnt, const unsigned* __restrict__ cv,
    const unsigned short* __restrict__ gt,
    const unsigned char* __restrict__ f1, const unsigned char* __restrict__ f2,
    unsigned short* __restrict__ y1) {
    int r = blockIdx.x * 32 + (threadIdx.x >> 3);
    int t = threadIdx.x & 7;            // 8 bf16 features per lane
    if (r >= N_TOT) return;
    // item-row demand check (user/bundle rows always needed)
    if (r >= OFF1 + NU && r < OFF2) { if (!f1[r - OFF1 - NU]) return; }
    else if (r >= OFF2 + NB)        { if (!f2[r - OFF2 - NB]) return; }
    int deg = cnt[r]; if (deg > CAP) deg = CAP;
    const unsigned* ce = cv + (size_t)r * CAP;
    float a[8];
#pragma unroll
    for (int k = 0; k < 8; ++k) a[k] = 0.f;
    int j = 0;
    for (; j + 3 < deg; j += 4) {
        int c[4]; float v[4]; uint4 u[4];
#pragma unroll
        for (int k = 0; k < 4; ++k) edge_decode(ce[j + k], c[k], v[k]);
#pragma unroll
        for (int k = 0; k < 4; ++k)
            u[k] = *(const uint4*)(gt + (((size_t)c[k]) << 6) + t * 8);
#pragma unroll
        for (int k = 0; k < 4; ++k) {
            a[0] = fmaf(v[k], bflo(u[k].x), a[0]); a[1] = fmaf(v[k], bfhi(u[k].x), a[1]);
            a[2] = fmaf(v[k], bflo(u[k].y), a[2]); a[3] = fmaf(v[k], bfhi(u[k].y), a[3]);
            a[4] = fmaf(v[k], bflo(u[k].z), a[4]); a[5] = fmaf(v[k], bfhi(u[k].z), a[5]);
            a[6] = fmaf(v[k], bflo(u[k].w), a[6]); a[7] = fmaf(v[k], bfhi(u[k].w), a[7]);
        }
    }
    for (; j < deg; ++j) {
        int c0; float v0;
        edge_decode(ce[j], c0, v0);
        uint4 u0 = *(const uint4*)(gt + (((size_t)c0) << 6) + t * 8);
        a[0] = fmaf(v0, bflo(u0.x), a[0]); a[1] = fmaf(v0, bfhi(u0.x), a[1]);
        a[2] = fmaf(v0, bflo(u0.y), a[2]); a[3] = fmaf(v0, bfhi(u0.y), a[3]);
        a[4] = fmaf(v0, bflo(u0.z), a[4]); a[5] = fmaf(v0, bfhi(u0.z), a[5]);
        a[6] = fmaf(v0, bflo(u0.w), a[6]); a[7] = fmaf(v0, bfhi(u0.w), a[7]);
    }
    uint4 o;
    o.x = pack2(a[0], a[1]); o.y = pack2(a[2], a[3]);
    o.z = pack2(a[4], a[5]); o.w = pack2(a[6], a[7]);
    *(uint4*)(y1 + ((size_t)r << 6) + t * 8) = o;
}

// ---------------- K4: layer 2 + mean, demand-driven, compact output --------
__global__ __launch_bounds__(256) void k_spmm_l2(
    const int* __restrict__ cnt, const unsigned* __restrict__ cv,
    const int* __restrict__ users, const int* __restrict__ bundles,
    const unsigned short* __restrict__ y1, const unsigned short* __restrict__ gt,
    const unsigned char* __restrict__ fS,
    unsigned short* __restrict__ xc) {
    int s = blockIdx.x * 32 + (threadIdx.x >> 3);
    int t = threadIdx.x & 7;
    if (s >= L2_SLOTS) return;
    int r, g, sec;
    if (s < NI)                { if (!fS[s]) return;                   // R21
                                 r = OFF1 + NU + s;        g = GI_BASE + s;        sec = 1; }
    else if (s < 2 * NI)       { int i = s - NI; if (!fS[i]) return;   // R21
                                 r = OFF2 + NB + i;        g = GI_BASE + i;        sec = 2; }
    else {
        int q = s - 2 * NI;
        if (q < BATCH)            { int u = users[q];             r = u;         g = u;            sec = 0; }
        else if (q < 2 * BATCH)   { int u = users[q - BATCH];     r = OFF1 + u;  g = u;            sec = 1; }
        else if (q < S_BIB - 2 * NI) { int b = bundles[q - 2 * BATCH];
                                    r = NU + b;    g = GB_BASE + b;  sec = 0; }
        else                      { int b = bundles[q - (S_BIB - 2 * NI)];
                                    r = OFF2 + b;  g = GB_BASE + b;  sec = 2; }
    }
    // inverse map: global feature idx -> y1 row in this section
    auto y1row = [&](int gg) -> int {
        if (sec == 0) return gg;                       // UB
        if (sec == 2) return OFF2 - GB_BASE + gg;      // BI
        return OFF1 + ((gg < NU) ? gg : gg - NB);      // UI
    };
    int deg = cnt[r]; if (deg > CAP) deg = CAP;
    const unsigned* ce = cv + (size_t)r * CAP;
    float a[8];
#pragma unroll
    for (int k = 0; k < 8; ++k) a[k] = 0.f;
    int j = 0;
    for (; j + 3 < deg; j += 4) {
        int c[4]; float v[4]; uint4 u[4];
#pragma unroll
        for (int k = 0; k < 4; ++k) edge_decode(ce[j + k], c[k], v[k]);
#pragma unroll
        for (int k = 0; k < 4; ++k)
            u[k] = *(const uint4*)(y1 + (((size_t)y1row(c[k])) << 6) + t * 8);
#pragma unroll
        for (int k = 0; k < 4; ++k) {
            a[0] = fmaf(v[k], bflo(u[k].x), a[0]); a[1] = fmaf(v[k], bfhi(u[k].x), a[1]);
            a[2] = fmaf(v[k], bflo(u[k].y), a[2]); a[3] = fmaf(v[k], bfhi(u[k].y), a[3]);
            a[4] = fmaf(v[k], bflo(u[k].z), a[4]); a[5] = fmaf(v[k], bfhi(u[k].z), a[5]);
            a[6] = fmaf(v[k], bflo(u[k].w), a[6]); a[7] = fmaf(v[k], bfhi(u[k].w), a[7]);
        }
    }
    for (; j < deg; ++j) {
        int c0; float v0;
        edge_decode(ce[j], c0, v0);
        uint4 u0 = *(const uint4*)(y1 + (((size_t)y1row(c0)) << 6) + t * 8);
        a[0] = fmaf(v0, bflo(u0.x), a[0]); a[1] = fmaf(v0, bfhi(u0.x), a[1]);
        a[2] = fmaf(v0, bflo(u0.y), a[2]); a[3] = fmaf(v0, bfhi(u0.y), a[3]);
        a[4] = fmaf(v0, bflo(u0.z), a[4]); a[5] = fmaf(v0, bfhi(u0.z), a[5]);
        a[6] = fmaf(v0, bflo(u0.w), a[6]); a[7] = fmaf(v0, bfhi(u0.w), a[7]);
    }
    uint4 fx = *(const uint4*)(gt + ((size_t)g << 6) + t * 8);   // original feature
    uint4 yx = *(const uint4*)(y1 + ((size_t)r << 6) + t * 8);
    constexpr float k3 = 1.0f / 3.0f;
    float o[8];
    o[0] = (bflo(fx.x) + bflo(yx.x) + a[0]) * k3;
    o[1] = (bfhi(fx.x) + bfhi(yx.x) + a[1]) * k3;
    o[2] = (bflo(fx.y) + bflo(yx.y) + a[2]) * k3;
    o[3] = (bfhi(fx.y) + bfhi(yx.y) + a[3]) * k3;
    o[4] = (bflo(fx.z) + bflo(yx.z) + a[4]) * k3;
    o[5] = (bfhi(fx.z) + bfhi(yx.z) + a[5]) * k3;
    o[6] = (bflo(fx.w) + bflo(yx.w) + a[6]) * k3;
    o[7] = (bfhi(fx.w) + bfhi(yx.w) + a[7]) * k3;
    uint4 w;
    w.x = pack2(o[0], o[1]); w.y = pack2(o[2], o[3]);
    w.z = pack2(o[4], o[5]); w.w = pack2(o[6], o[7]);
    *(uint4*)(xc + ((size_t)s << 6) + t * 8) = w;
}

// ---------------- K5: scoring + fused BPR loss (R18, kept) ----------------
__global__ __launch_bounds__(256) void k_score(
    const int* __restrict__ bundles,
    const int* __restrict__ bundle_items,
    const unsigned short* __restrict__ xc,
    const float* __restrict__ cw1, const float* __restrict__ cb1,
    const float* __restrict__ cw2, const float* __restrict__ cb2,
    const float* __restrict__ sw1, const float* __restrict__ sb1,
    const float* __restrict__ sw2, const float* __restrict__ sb2,
    float* __restrict__ accum, unsigned* __restrict__ tick,
    float* __restrict__ out) {
    const int t  = threadIdx.x;
    const int wv = t >> 6;               // wave 0..3 -> candidate
    const int ln = t & 63;
    const int n  = blockIdx.x * 4 + wv;  // grid = BATCH*NCAND/4
    const int g8 = ln >> 3;              // item subgroup (8 items in flight)
    const int l8 = ln & 7;               // feature octet within item
    const int uq = n >> 1;               // batch index
    const int b = bundles[n];

    __shared__ unsigned sh_it[4][MAXDEG][32];  // items_ui bf16: 50 x 64 (25.6 KB)
    __shared__ float sh_r[4][2][MAXDEG];       // dual dot results
    __shared__ float sh_syn[4][2 * D];         // [hcore | hfringe]
    __shared__ float sh_h1[4][D];              // relu(syn @ sw1 + sb1)
    __shared__ float sh_sc[4];                 // per-wave final scores

    int my_idx = (ln < MAXDEG) ? bundle_items[(size_t)b * MAXDEG + ln] : PAD_IDX;
    unsigned long long vmask = __ballot(my_idx != PAD_IDX);

    uint4 ufr = *(const uint4*)(xc + (((size_t)(S_UIU + uq)) << 6) + l8 * 8);
    uint4 bfr = *(const uint4*)(xc + (((size_t)(S_BIB + n)) << 6) + l8 * 8);
    float uf0 = bflo(ufr.x), uf1 = bfhi(ufr.x), uf2 = bflo(ufr.y), uf3 = bfhi(ufr.y);
    float uf4 = bflo(ufr.z), uf5 = bfhi(ufr.z), uf6 = bflo(ufr.w), uf7 = bfhi(ufr.w);
    float bf0 = bflo(bfr.x), bf1_ = bfhi(bfr.x), bf2 = bflo(bfr.y), bf3 = bfhi(bfr.y);
    float bf4 = bflo(bfr.z), bf5 = bfhi(bfr.z), bf6 = bflo(bfr.w), bf7 = bfhi(bfr.w);

    // --- P1: 50 dual dots, 8 items in flight x 8 lanes x 8 features ---
    for (int iter = 0; iter < (MAXDEG + 7) / 8; ++iter) {
        int m = iter * 8 + g8;
        if (m >= MAXDEG) continue;
        int it = __shfl(my_idx, m);
        uint4 iu = make_uint4(0, 0, 0, 0);
        float pu = 0.f, pb = 0.f;
        if (it != PAD_IDX) {
            iu = *(const uint4*)(xc + (((size_t)it) << 6) + l8 * 8);              // UI item
            uint4 ib = *(const uint4*)(xc + (((size_t)(NI + it)) << 6) + l8 * 8); // BI item
            pu = uf0 * bflo(iu.x) + uf1 * bfhi(iu.x) + uf2 * bflo(iu.y) + uf3 * bfhi(iu.y)
               + uf4 * bflo(iu.z) + uf5 * bfhi(iu.z) + uf6 * bflo(iu.w) + uf7 * bfhi(iu.w);
            pb = bf0 * bflo(ib.x) + bf1_ * bfhi(ib.x) + bf2 * bflo(ib.y) + bf3 * bfhi(ib.y)
               + bf4 * bflo(ib.z) + bf5 * bfhi(ib.z) + bf6 * bflo(ib.w) + bf7 * bfhi(ib.w);
        }
        *(uint4*)&sh_it[wv][m][l8 * 4] = iu;   // pads stash zeros
#pragma unroll
        for (int off = 4; off > 0; off >>= 1) {
            pu += __shfl_down(pu, off, 8);
            pb += __shfl_down(pb, off, 8);
        }
        if (l8 == 0) { sh_r[wv][0][m] = pu; sh_r[wv][1][m] = pb; }
    }
    __builtin_amdgcn_wave_barrier();

    // --- P2: core MLP (2->32->1), lane m = item m ---
    float logit = -INFINITY;
    if (ln < MAXDEG && my_idx != PAD_IDX) {
        float rU = sh_r[wv][0][ln], rB = sh_r[wv][1][ln];
        float acc = cb2[0];
#pragma unroll
        for (int j = 0; j < 32; ++j) {
            float h = fmaf(rU, cw1[j], fmaf(rB, cw1[32 + j], cb1[j]));
            h = fmaxf(h, 0.f);
            acc = fmaf(h, cw2[j], acc);
        }
        logit = acc;
    }

    // --- P3: wave-parallel softmax + top-3 ---
    float mx = logit;
#pragma unroll
    for (int off = 32; off > 0; off >>= 1) mx = fmaxf(mx, __shfl_xor(mx, off));
    float e = expf(logit - mx);            // pad lanes: exp(-inf)=0
    float sm = e;
#pragma unroll
    for (int off = 32; off > 0; off >>= 1) sm += __shfl_xor(sm, off);
    float p = e / sm;

    int ti[CORE_K]; float tp[CORE_K];
    float vsel = p;
#pragma unroll
    for (int k = 0; k < CORE_K; ++k) {
        float vv = vsel; int ii = ln;
#pragma unroll
        for (int off = 32; off > 0; off >>= 1) {
            float v2 = __shfl_xor(vv, off);
            int   i2 = __shfl_xor(ii, off);
            if (v2 > vv || (v2 == vv && i2 < ii)) { vv = v2; ii = i2; }
        }
        ti[k] = ii; tp[k] = vv;            // uniform across wave
        if (ln == ii) vsel = -1.f;
    }
    float tinv = 1.f / (tp[0] + tp[1] + tp[2] + 1e-10f);
    tp[0] *= tinv; tp[1] *= tinv; tp[2] *= tinv;

    // --- P4: h_core / h_fringe, lane = feature dim ---
    int ti0 = ti[0], ti1 = ti[1], ti2 = ti[2];
    const int ui_w = ln >> 1;
    const bool hi = (ln & 1);
    auto feat = [&](int m) -> float {
        unsigned w = sh_it[wv][m][ui_w];
        return hi ? bfhi(w) : bflo(w);
    };
    float hcore = feat(ti0) * tp[0] + feat(ti1) * tp[1] + feat(ti2) * tp[2];
    float fsum = 0.f;
#pragma unroll 10
    for (int m = 0; m < MAXDEG; ++m) fsum += feat(m);   // pads contribute 0
    int fcnt = __popcll(vmask);
#pragma unroll
    for (int k = 0; k < CORE_K; ++k) {
        if ((vmask >> ti[k]) & 1ull) { fsum -= feat(ti[k]); fcnt--; }
    }
    float hfr = fsum / fmaxf((float)fcnt, 1.f);
    sh_syn[wv][ln] = hcore;
    sh_syn[wv][D + ln] = hfr;
    __builtin_amdgcn_wave_barrier();

    // --- P5: synergy MLP (128->64 relu ->64), whole wave, LDS broadcast ---
    float h1 = sb1[ln];
#pragma unroll 8
    for (int k0 = 0; k0 < 32; ++k0) {
        float4 s4 = *(const float4*)&sh_syn[wv][k0 * 4];
        h1 = fmaf(s4.x, sw1[(k0 * 4 + 0) * D + ln], h1);
        h1 = fmaf(s4.y, sw1[(k0 * 4 + 1) * D + ln], h1);
        h1 = fmaf(s4.z, sw1[(k0 * 4 + 2) * D + ln], h1);
        h1 = fmaf(s4.w, sw1[(k0 * 4 + 3) * D + ln], h1);
    }
    sh_h1[wv][ln] = fmaxf(h1, 0.f);
    __builtin_amdgcn_wave_barrier();
    float phi = sb2[ln];
#pragma unroll 8
    for (int k0 = 0; k0 < 16; ++k0) {
        float4 s4 = *(const float4*)&sh_h1[wv][k0 * 4];
        phi = fmaf(s4.x, sw2[(k0 * 4 + 0) * D + ln], phi);
        phi = fmaf(s4.y, sw2[(k0 * 4 + 1) * D + ln], phi);
        phi = fmaf(s4.z, sw2[(k0 * 4 + 2) * D + ln], phi);
        phi = fmaf(s4.w, sw2[(k0 * 4 + 3) * D + ln], phi);
    }

    // --- P6: final score ---
    float hat = hcore + phi;
    float uui = bf1(xc + (((size_t)(S_UIU + uq)) << 6) + ln);
    float ubu = bf1(xc + (((size_t)(S_UBU + uq)) << 6) + ln);
    float ubb = bf1(xc + (((size_t)(S_UBB + n)) << 6) + ln);
    float part = wave_sum64(uui * ubb + ubu * hat);
    if (ln == 0) sh_sc[wv] = part;

    // --- fused BPR loss tail: pairs (wv 0,1) and (wv 2,3) ---
    __syncthreads();
    if (t == 0) {
        float x01 = sh_sc[1] - sh_sc[0];
        float x23 = sh_sc[3] - sh_sc[2];
        float spv = fmaxf(x01, 0.f) + log1pf(expf(-fabsf(x01)))
                  + fmaxf(x23, 0.f) + log1pf(expf(-fabsf(x23)));
        atomicAdd(accum, spv * (1.0f / (float)BATCH));
        __threadfence();
        unsigned old = atomicAdd(tick, 1u);
        if (old == gridDim.x - 1) {          // last block: publish
            __threadfence();
            float total = atomicAdd(accum, 0.0f);   // coherent RMW read
            out[0] = total;
        }
    }
}

extern "C" void kernel_launch(void* const* d_in, const int* in_sizes, int n_in,
                              void* d_out, int out_size, void* d_ws, size_t ws_size,
                              hipStream_t stream) {
    const float* users_feature   = (const float*)d_in[0];
    const float* bundles_feature = (const float*)d_in[1];
    const float* items_feature   = (const float*)d_in[2];
    const float* cw1 = (const float*)d_in[3];
    const float* cb1 = (const float*)d_in[4];
    const float* cw2 = (const float*)d_in[5];
    const float* cb2 = (const float*)d_in[6];
    const float* sw1 = (const float*)d_in[7];
    const float* sb1 = (const float*)d_in[8];
    const float* sw2 = (const float*)d_in[9];
    const float* sb2 = (const float*)d_in[10];
    const float* ub_val = (const float*)d_in[11];
    const float* ui_val = (const float*)d_in[12];
    const float* bi_val = (const float*)d_in[13];
    const int* users   = (const int*)d_in[14];
    const int* bundles = (const int*)d_in[15];
    const int* ub_row = (const int*)d_in[16];
    const int* ub_col = (const int*)d_in[17];
    const int* ui_row = (const int*)d_in[18];
    const int* ui_col = (const int*)d_in[19];
    const int* bi_row = (const int*)d_in[20];
    const int* bi_col = (const int*)d_in[21];
    const int* bundle_items = (const int*)d_in[22];
    const int E_UB = in_sizes[11], E_UI = in_sizes[12], E_BI = in_sizes[13];
    const int E_TOT = E_UB + E_UI + E_BI;

    // workspace layout (4-byte units), ~163 MB (< ~167 MB proven in R1)
    float* ws = (float*)d_ws;
    size_t off = 0;
    unsigned short* gt  = (unsigned short*)(ws + off); off += (size_t)NGF * 32;      // 21.8 MB
    unsigned short* y1b = (unsigned short*)(ws + off); off += (size_t)N_TOT * 32;    // 43.5 MB
    unsigned* cv  = (unsigned*)(ws + off); off += (size_t)N_TOT * CAP;               // 65.3 MB
    // stage (32.7 MB) overlays xc (27.2 MB): stage dead after k_bin2,
    // xc written only by k_spmm_l2 (later kernel).
    uint2* stage = (uint2*)(ws + off);
    unsigned short* xc = (unsigned short*)(ws + off);
    off += (size_t)NBUCK * BCAP * 2;                                                 // 32.7 MB
    // memset region: [bcnt | tick | accum | fS | f1 | f2 | du | db]
    int*   bcnt   = (int*)(ws + off); off += NBUCK;
    unsigned* tick = (unsigned*)(ws + off); off += 1;
    float* accum  = (float*)(ws + off); off += 1;
    unsigned char* fS = (unsigned char*)(ws + off); off += NI / 4;
    unsigned char* f1 = (unsigned char*)(ws + off); off += NI / 4;
    unsigned char* f2 = (unsigned char*)(ws + off); off += NI / 4;
    unsigned char* du = (unsigned char*)(ws + off); off += NU / 4;
    unsigned char* db = (unsigned char*)(ws + off); off += NB / 4;
    int*   cnt    = (int*)(ws + off); off += N_TOT;
    if (ws_size < off * sizeof(float)) return;  // fail loudly (wrong answer)

    // zero bcnt + tick + accum + flags (fS,f1,f2,du,db) in one memset
    hipMemsetAsync(bcnt, 0, (NBUCK + 2) * sizeof(int) + 3 * NI + NU + NB, stream);

    // K1: coarse binning + feature convert + demand seeds (merged; R28)
    const int nb1 = (E_TOT + P1_EPB - 1) / P1_EPB;
    const int ncvt = (int)(((size_t)NGF * 16 + P1_TPB - 1) / P1_TPB);
    const int nb2 = nb1 + ncvt;
    const int nb3 = nb2 + MARK_A_BLOCKS;
    k_bin1cvt<<<nb3 + MARK_D_BLOCKS, P1_TPB, 0, stream>>>(
        ub_row, ub_col, ub_val, ui_row, ui_col, ui_val, bi_row, bi_col, bi_val,
        E_UB, E_UI, E_BI, nb1, nb2, nb3, bcnt, stage,
        users_feature, bundles_feature, items_feature, gt,
        users, bundles, bundle_items, fS, du, db);

    // K2: per-bucket refine + f1/f2 marking (k_mark folded in)
    k_bin2<<<NBUCK, 1024, 0, stream>>>(bcnt, stage, du, db, cnt, cv, f1, f2);

    // K3: demand-driven layer-1 gather
    k_spmm_l1<<<(N_TOT + 31) / 32, 256, 0, stream>>>(cnt, cv, gt, f1, f2, y1b);

    // K4: demand-driven layer 2 -> compact xc
    k_spmm_l2<<<(L2_SLOTS + 31) / 32, 256, 0, stream>>>(
        cnt, cv, users, bundles, y1b, gt, fS, xc);

    // K5: scoring + fused loss
    k_score<<<(BATCH * NCAND) / 4, 256, 0, stream>>>(
        bundles, bundle_items, xc,
        cw1, cb1, cw2, cb2, sw1, sb1, sw2, sb2,
        accum, tick, (float*)d_out);
}